// Round 6
// baseline (1294.606 us; speedup 1.0000x reference)
//
#include <hip/hip_runtime.h>
#include <hip/hip_bf16.h>

// ---------------------------------------------------------------------------
// Mask-RCNN RoI head. Round 5: fc GEMM split-K 4->8 (512 blocks = 2/CU) to
// overlap staging latency across co-resident blocks (was 1 block/CU, all
// pipes <15% busy). Cp partials now 32MB; conv/deconv weight repacks moved
// after the fc phase so Wr/Wd alias the dead Cp region (ws top ~93MB).
// ---------------------------------------------------------------------------

#define NUM_CLASSES 81
#define CDIM 256
#define RTOT 1024
#define RMASK 256
#define LOG1000_16 4.135166556742356f

typedef _Float16 half8v __attribute__((ext_vector_type(8)));
typedef _Float16 half4v __attribute__((ext_vector_type(4)));
typedef float    float4v __attribute__((ext_vector_type(4)));

// ---------------------------------------------------------------------------
// K1: roi_align out_size=7 -> bf fp32 (1024 x 12544). Block=(roi, 64ch grp).
// ---------------------------------------------------------------------------
__global__ __launch_bounds__(256) void roi_align7_kernel(
    const float* __restrict__ f0, const float* __restrict__ f1,
    const float* __restrict__ f2, const float* __restrict__ f3,
    const float* __restrict__ props, const int* __restrict__ bidx,
    float* __restrict__ bf)
{
    int r  = blockIdx.x;
    int cg = blockIdx.y;          // 4 groups of 64 channels
    int t = threadIdx.x;
    if (t >= 196) return;
    int p  = t % 49;
    int cl = t / 49;              // 4 channel lanes
    int oy = p / 7, ox = p % 7;

    float x1 = props[r*4+0], y1 = props[r*4+1];
    float x2 = props[r*4+2], y2 = props[r*4+3];
    float area = fmaxf(x2-x1, 0.f) * fmaxf(y2-y1, 0.f);
    float lf = floorf(4.f + log2f(sqrtf(area)/224.f + 1e-6f));
    lf = fminf(fmaxf(lf, 2.f), 5.f);
    int lvl = (int)lf - 2;

    const float* feat; int H, W; float scale;
    if (lvl == 0)      { feat = f0; H = 200; W = 200; scale = 0.25f; }
    else if (lvl == 1) { feat = f1; H = 100; W = 100; scale = 0.125f; }
    else if (lvl == 2) { feat = f2; H = 50;  W = 50;  scale = 0.0625f; }
    else               { feat = f3; H = 25;  W = 25;  scale = 0.03125f; }
    int b = bidx[r];

    float x1s = x1*scale, y1s = y1*scale;
    float rw = fmaxf(x2*scale - x1s, 1.f);
    float rh = fmaxf(y2*scale - y1s, 1.f);

    int   offs[4];
    float w00[4], w01[4], w10[4], w11[4];
    #pragma unroll
    for (int sy = 0; sy < 2; ++sy) {
        int iy = oy*2 + sy;
        float gy = ((float)iy + 0.5f) / 14.f;
        float yc = y1s + rh*gy;
        bool  yv = (yc > -1.f) && (yc < (float)H);
        float ycl = fminf(fmaxf(yc, 0.f), (float)(H-1));
        int   y0  = (int)fminf(floorf(ycl), (float)(H-2));
        float ly  = ycl - (float)y0;
        #pragma unroll
        for (int sx = 0; sx < 2; ++sx) {
            int ix = ox*2 + sx;
            float gx = ((float)ix + 0.5f) / 14.f;
            float xc = x1s + rw*gx;
            bool  xv = (xc > -1.f) && (xc < (float)W);
            float xcl = fminf(fmaxf(xc, 0.f), (float)(W-1));
            int   x0  = (int)fminf(floorf(xcl), (float)(W-2));
            float lx  = xcl - (float)x0;
            float m = (yv && xv) ? 1.f : 0.f;
            int s = sy*2 + sx;
            offs[s] = y0*W + x0;
            w00[s] = (1.f-ly)*(1.f-lx)*m;
            w01[s] = (1.f-ly)*lx*m;
            w10[s] = ly*(1.f-lx)*m;
            w11[s] = ly*lx*m;
        }
    }

    size_t HW = (size_t)H * W;
    #pragma unroll 4
    for (int k = 0; k < 16; ++k) {
        int c = cg*64 + cl + k*4;
        const float* fb = feat + ((size_t)b*CDIM + c) * HW;
        float acc = 0.f;
        #pragma unroll
        for (int s = 0; s < 4; ++s) {
            const float* q = fb + offs[s];
            acc += w00[s]*q[0] + w01[s]*q[1] + w10[s]*q[W] + w11[s]*q[W+1];
        }
        bf[(size_t)r*12544 + c*49 + p] = acc * 0.25f;
    }
}

// ---------------------------------------------------------------------------
// K2/K3: split-fp16 MFMA GEMM, partials: Cp[kz][1024][1024] (no bias/act).
// grid (8, 8, KZ); KS = K/KZ must be a multiple of 32.
// ---------------------------------------------------------------------------
#define FSTR 40

__global__ __launch_bounds__(256, 1) void gemm_splitk_f16x3(
    const float* __restrict__ A, const float* __restrict__ B,
    float* __restrict__ Cp, int K, int KS)
{
    __shared__ _Float16 Ah[128*FSTR];
    __shared__ _Float16 Al[128*FSTR];
    __shared__ _Float16 Bh[128*FSTR];
    __shared__ _Float16 Bl[128*FSTR];

    int t = threadIdx.x;
    int lane = t & 63, wave = t >> 6;
    int wm = wave >> 1, wn = wave & 1;
    int ln = lane & 15, q = lane >> 4;
    int bn = blockIdx.x, bm = blockIdx.y, kz = blockIdx.z;

    const float* Abase = A + (size_t)(bm*128)*K + (size_t)kz*KS;
    const float* Bbase = B + (size_t)(bn*128)*K + (size_t)kz*KS;

    float4v acc1[4][4], acc2[4][4];
    #pragma unroll
    for (int i = 0; i < 4; ++i)
        #pragma unroll
        for (int j = 0; j < 4; ++j) {
            acc1[i][j] = (float4v){0.f,0.f,0.f,0.f};
            acc2[i][j] = (float4v){0.f,0.f,0.f,0.f};
        }

    for (int k0 = 0; k0 < KS; k0 += 32) {
        __syncthreads();
        #pragma unroll
        for (int it = 0; it < 2; ++it) {
            int idx = it*256 + t;
            int row = idx >> 2, c8 = (idx & 3) * 8;
            {
                const float* pa = Abase + (size_t)row*K + k0 + c8;
                float4 v0 = *(const float4*)pa;
                float4 v1 = *(const float4*)(pa + 4);
                float vv[8] = {v0.x,v0.y,v0.z,v0.w,v1.x,v1.y,v1.z,v1.w};
                half8v h, l;
                #pragma unroll
                for (int j = 0; j < 8; ++j) {
                    _Float16 hj = (_Float16)vv[j];
                    h[j] = hj;
                    l[j] = (_Float16)((vv[j] - (float)hj) * 2048.f);
                }
                *(half8v*)&Ah[row*FSTR + c8] = h;
                *(half8v*)&Al[row*FSTR + c8] = l;
            }
            {
                const float* pb = Bbase + (size_t)row*K + k0 + c8;
                float4 v0 = *(const float4*)pb;
                float4 v1 = *(const float4*)(pb + 4);
                float vv[8] = {v0.x,v0.y,v0.z,v0.w,v1.x,v1.y,v1.z,v1.w};
                half8v h, l;
                #pragma unroll
                for (int j = 0; j < 8; ++j) {
                    _Float16 hj = (_Float16)vv[j];
                    h[j] = hj;
                    l[j] = (_Float16)((vv[j] - (float)hj) * 2048.f);
                }
                *(half8v*)&Bh[row*FSTR + c8] = h;
                *(half8v*)&Bl[row*FSTR + c8] = l;
            }
        }
        __syncthreads();

        half8v afh[4], afl[4], bfh[4], bfl[4];
        #pragma unroll
        for (int i = 0; i < 4; ++i) {
            int ra = (wm*64 + i*16 + ln)*FSTR + q*8;
            afh[i] = *(const half8v*)&Ah[ra];
            afl[i] = *(const half8v*)&Al[ra];
            int rb = (wn*64 + i*16 + ln)*FSTR + q*8;
            bfh[i] = *(const half8v*)&Bh[rb];
            bfl[i] = *(const half8v*)&Bl[rb];
        }
        #pragma unroll
        for (int i = 0; i < 4; ++i) {
            #pragma unroll
            for (int j = 0; j < 4; ++j) {
                acc1[i][j] = __builtin_amdgcn_mfma_f32_16x16x32_f16(
                    afh[i], bfh[j], acc1[i][j], 0, 0, 0);
                acc2[i][j] = __builtin_amdgcn_mfma_f32_16x16x32_f16(
                    afh[i], bfl[j], acc2[i][j], 0, 0, 0);
                acc2[i][j] = __builtin_amdgcn_mfma_f32_16x16x32_f16(
                    afl[i], bfh[j], acc2[i][j], 0, 0, 0);
            }
        }
    }

    float* Cpz = Cp + (size_t)kz*1024*1024;
    #pragma unroll
    for (int i = 0; i < 4; ++i) {
        #pragma unroll
        for (int j = 0; j < 4; ++j) {
            int col = bn*128 + wn*64 + j*16 + ln;
            #pragma unroll
            for (int reg = 0; reg < 4; ++reg) {
                int row = bm*128 + wm*64 + i*16 + q*4 + reg;
                Cpz[(size_t)row*1024 + col] =
                    acc1[i][j][reg] + acc2[i][j][reg] * (1.f/2048.f);
            }
        }
    }
}

// reduce 8 split-K partials + bias + relu -> out (1024x1024 fp32)
__global__ __launch_bounds__(256) void fc_reduce_kernel(
    const float* __restrict__ Cp, const float* __restrict__ bias,
    float* __restrict__ out)
{
    int i = blockIdx.x*256 + threadIdx.x;
    const float4* p = (const float4*)Cp;
    float sx = 0.f, sy = 0.f, sz = 0.f, sw = 0.f;
    #pragma unroll
    for (int j = 0; j < 8; ++j) {
        float4 s = p[i + j*262144];
        sx += s.x; sy += s.y; sz += s.z; sw += s.w;
    }
    float4 b4 = ((const float4*)bias)[i & 255];
    float4 v;
    v.x = fmaxf(sx + b4.x, 0.f);
    v.y = fmaxf(sy + b4.y, 0.f);
    v.z = fmaxf(sz + b4.z, 0.f);
    v.w = fmaxf(sw + b4.w, 0.f);
    ((float4*)out)[i] = v;
}

// ---------------------------------------------------------------------------
// K4: cls head (softmax scores + labels)
// ---------------------------------------------------------------------------
__global__ __launch_bounds__(128) void cls_head_kernel(
    const float* __restrict__ x, const float* __restrict__ w,
    const float* __restrict__ b, float* __restrict__ scores,
    int* __restrict__ labels)
{
    __shared__ float xr[1024];
    __shared__ float lg[NUM_CLASSES];
    __shared__ float red[2];
    int r = blockIdx.x, t = threadIdx.x;
    const float4* xp = (const float4*)(x + (size_t)r*1024);
    float4* xr4 = (float4*)xr;
    for (int i = t; i < 256; i += 128) xr4[i] = xp[i];
    __syncthreads();
    if (t < NUM_CLASSES) {
        const float* wr = w + (size_t)t*1024;
        float acc = b[t];
        for (int k = 0; k < 1024; k += 4)
            acc += xr[k]*wr[k] + xr[k+1]*wr[k+1] + xr[k+2]*wr[k+2] + xr[k+3]*wr[k+3];
        lg[t] = acc;
    }
    __syncthreads();
    if (t == 0) {
        float mx = lg[0];
        for (int j = 1; j < NUM_CLASSES; ++j) mx = fmaxf(mx, lg[j]);
        red[0] = mx;
    }
    __syncthreads();
    float mx = red[0];
    if (t < NUM_CLASSES) lg[t] = expf(lg[t] - mx);
    __syncthreads();
    if (t == 0) {
        float s = 0.f;
        for (int j = 0; j < NUM_CLASSES; ++j) s += lg[j];
        red[1] = 1.f/s;
    }
    __syncthreads();
    if (t < NUM_CLASSES) scores[(size_t)r*NUM_CLASSES + t] = lg[t]*red[1];
    if (t == 0) {
        bool sel = (r < 128) || (r >= 512 && r < 640);
        if (sel) {
            int mi = (r < 128) ? r : r - 384;
            int best = 1; float bv = lg[1];
            for (int j = 2; j < NUM_CLASSES; ++j)
                if (lg[j] > bv) { bv = lg[j]; best = j; }
            labels[mi] = best;
        }
    }
}

// ---------------------------------------------------------------------------
// K5: bbox head (decode boxes + mboxes)
// ---------------------------------------------------------------------------
__global__ __launch_bounds__(384) void bbox_head_kernel(
    const float* __restrict__ x, const float* __restrict__ w,
    const float* __restrict__ bias, const float* __restrict__ props,
    const int* __restrict__ labels, float* __restrict__ boxes,
    float* __restrict__ mboxes)
{
    __shared__ float xr[1024];
    __shared__ float dl[NUM_CLASSES*4];
    int r = blockIdx.x, t = threadIdx.x;
    for (int i = t; i < 1024; i += 384) xr[i] = x[(size_t)r*1024 + i];
    __syncthreads();
    if (t < NUM_CLASSES*4) {
        const float* wr = w + (size_t)t*1024;
        float acc = bias[t];
        for (int k = 0; k < 1024; k += 4)
            acc += xr[k]*wr[k] + xr[k+1]*wr[k+1] + xr[k+2]*wr[k+2] + xr[k+3]*wr[k+3];
        dl[t] = acc;
    }
    __syncthreads();
    if (t < NUM_CLASSES) {
        float px1 = props[r*4+0], py1 = props[r*4+1];
        float px2 = props[r*4+2], py2 = props[r*4+3];
        float pw = px2 - px1, ph = py2 - py1;
        float cx = px1 + 0.5f*pw, cy = py1 + 0.5f*ph;
        float d0 = dl[t*4+0] * 0.1f;
        float d1 = dl[t*4+1] * 0.1f;
        float d2 = fminf(dl[t*4+2] * 0.2f, LOG1000_16);
        float d3 = fminf(dl[t*4+3] * 0.2f, LOG1000_16);
        float pcx = d0*pw + cx, pcy = d1*ph + cy;
        float qw = expf(d2)*pw, qh = expf(d3)*ph;
        float b0 = fminf(fmaxf(pcx - 0.5f*qw, 0.f), 800.f);
        float b1 = fminf(fmaxf(pcy - 0.5f*qh, 0.f), 800.f);
        float b2 = fminf(fmaxf(pcx + 0.5f*qw, 0.f), 800.f);
        float b3 = fminf(fmaxf(pcy + 0.5f*qh, 0.f), 800.f);
        size_t ob = ((size_t)r*NUM_CLASSES + t)*4;
        boxes[ob+0] = b0; boxes[ob+1] = b1; boxes[ob+2] = b2; boxes[ob+3] = b3;
        bool sel = (r < 128) || (r >= 512 && r < 640);
        if (sel) {
            int mi = (r < 128) ? r : r - 384;
            if (labels[mi] == t) {
                mboxes[mi*4+0] = b0; mboxes[mi*4+1] = b1;
                mboxes[mi*4+2] = b2; mboxes[mi*4+3] = b3;
            }
        }
    }
}

// ---------------------------------------------------------------------------
// K6: roi_align 14x14 -> transposed fp16 actT[mi][p][c]. Block=(roi,32ch grp).
// ---------------------------------------------------------------------------
__global__ __launch_bounds__(256) void roi_align14_kernel(
    const float* __restrict__ f0, const float* __restrict__ f1,
    const float* __restrict__ f2, const float* __restrict__ f3,
    const float* __restrict__ mboxes, const int* __restrict__ bidx,
    _Float16* __restrict__ outT)
{
    int mi = blockIdx.x;
    int cg = blockIdx.y;          // 8 groups of 32 channels
    int t = threadIdx.x;
    if (t >= 196) return;
    int oy = t / 14, ox = t % 14;

    float x1 = mboxes[mi*4+0], y1 = mboxes[mi*4+1];
    float x2 = mboxes[mi*4+2], y2 = mboxes[mi*4+3];
    float area = fmaxf(x2-x1, 0.f) * fmaxf(y2-y1, 0.f);
    float lf = floorf(4.f + log2f(sqrtf(area)/224.f + 1e-6f));
    lf = fminf(fmaxf(lf, 2.f), 5.f);
    int lvl = (int)lf - 2;

    const float* feat; int H, W; float scale;
    if (lvl == 0)      { feat = f0; H = 200; W = 200; scale = 0.25f; }
    else if (lvl == 1) { feat = f1; H = 100; W = 100; scale = 0.125f; }
    else if (lvl == 2) { feat = f2; H = 50;  W = 50;  scale = 0.0625f; }
    else               { feat = f3; H = 25;  W = 25;  scale = 0.03125f; }
    int ridx = (mi < 128) ? mi : mi + 384;
    int b = bidx[ridx];

    float x1s = x1*scale, y1s = y1*scale;
    float rw = fmaxf(x2*scale - x1s, 1.f);
    float rh = fmaxf(y2*scale - y1s, 1.f);

    int   offs[4];
    float w00[4], w01[4], w10[4], w11[4];
    #pragma unroll
    for (int sy = 0; sy < 2; ++sy) {
        int iy = oy*2 + sy;
        float gy = ((float)iy + 0.5f) / 28.f;
        float yc = y1s + rh*gy;
        bool  yv = (yc > -1.f) && (yc < (float)H);
        float ycl = fminf(fmaxf(yc, 0.f), (float)(H-1));
        int   y0  = (int)fminf(floorf(ycl), (float)(H-2));
        float ly  = ycl - (float)y0;
        #pragma unroll
        for (int sx = 0; sx < 2; ++sx) {
            int ix = ox*2 + sx;
            float gx = ((float)ix + 0.5f) / 28.f;
            float xc = x1s + rw*gx;
            bool  xv = (xc > -1.f) && (xc < (float)W);
            float xcl = fminf(fmaxf(xc, 0.f), (float)(W-1));
            int   x0  = (int)fminf(floorf(xcl), (float)(W-2));
            float lx  = xcl - (float)x0;
            float m = (yv && xv) ? 1.f : 0.f;
            int s = sy*2 + sx;
            offs[s] = y0*W + x0;
            w00[s] = (1.f-ly)*(1.f-lx)*m;
            w01[s] = (1.f-ly)*lx*m;
            w10[s] = ly*(1.f-lx)*m;
            w11[s] = ly*lx*m;
        }
    }

    size_t HW = (size_t)H * W;
    _Float16* orow = outT + ((size_t)mi*196 + t)*CDIM + cg*32;
    const float* fbase = feat + ((size_t)b*CDIM + cg*32) * HW;
    #pragma unroll
    for (int c8 = 0; c8 < 32; c8 += 8) {
        half8v hv;
        #pragma unroll
        for (int cc = 0; cc < 8; ++cc) {
            const float* fb = fbase + (size_t)(c8+cc) * HW;
            float acc = 0.f;
            #pragma unroll
            for (int s = 0; s < 4; ++s) {
                const float* q = fb + offs[s];
                acc += w00[s]*q[0] + w01[s]*q[1] + w10[s]*q[W] + w11[s]*q[W+1];
            }
            hv[cc] = (_Float16)(acc * 0.25f);
        }
        *(half8v*)(orow + c8) = hv;
    }
}

// ---------------------------------------------------------------------------
// Weight repacks
// ---------------------------------------------------------------------------
__global__ __launch_bounds__(256) void repack_wts_kernel(
    const float* __restrict__ w, _Float16* __restrict__ Wr)
{
    int i = blockIdx.x*256 + threadIdx.x;   // 4*9*256*256
    int ci = i & 255;
    int rest = i >> 8;
    int co = rest & 255;
    int rest2 = rest >> 8;
    int tap = rest2 % 9;
    int l = rest2 / 9;
    Wr[i] = (_Float16)w[(((size_t)(l*256 + co)*256 + ci)*9) + tap];
}

// deconv_w[c][o][p][q] fp32 -> Wd[n=o*4+p*2+q][c] fp16  (pure transpose)
__global__ __launch_bounds__(256) void repack_dw_kernel(
    const float* __restrict__ dw, _Float16* __restrict__ Wd)
{
    int i = blockIdx.x*256 + threadIdx.x;   // 1024*256
    int n = i >> 8, k = i & 255;
    Wd[i] = (_Float16)dw[(size_t)k*1024 + n];
}

// ---------------------------------------------------------------------------
// K7: conv3x3+bias+relu as fp16 MFMA implicit GEMM.
// ---------------------------------------------------------------------------
#define PSTR 40

__global__ __launch_bounds__(256) void conv3x3_mfma_kernel(
    const _Float16* __restrict__ inT, const _Float16* __restrict__ Wr,
    const float* __restrict__ bias, _Float16* __restrict__ outT, int layer)
{
    __shared__ _Float16 lin[256*PSTR];   // 20 KiB

    int t = threadIdx.x;
    int lane = t & 63;
    int wave = t >> 6;
    int ln = lane & 15;
    int q  = lane >> 4;
    int q8 = q*8;
    int r  = blockIdx.x >> 2;
    int bc = blockIdx.x & 3;
    int co_w = bc*64 + wave*16;

    const _Float16* WrL = Wr + (size_t)layer*9*256*256;
    const _Float16* inR = inT + (size_t)r*196*256;

    for (int i = t; i < 256*PSTR; i += 256) lin[i] = (_Float16)0.f;

    float4v acc[13];
    #pragma unroll
    for (int nt = 0; nt < 13; ++nt) acc[nt] = (float4v){0.f,0.f,0.f,0.f};

    for (int ci0 = 0; ci0 < 256; ci0 += 32) {
        __syncthreads();
        for (int idx = t; idx < 784; idx += 256) {
            int p = idx >> 2, g = idx & 3;
            float4 v = *(const float4*)(inR + (size_t)p*256 + ci0 + g*8);
            int row = (p*37450) >> 19;
            int col = p - row*14;
            *(float4*)&lin[((row+1)*16 + (col+1))*PSTR + g*8] = v;
        }
        __syncthreads();

        half8v aw[9];
        #pragma unroll
        for (int tap = 0; tap < 9; ++tap)
            aw[tap] = *(const half8v*)(WrL + ((size_t)tap*256 + co_w + ln)*256 + ci0 + q8);

        #pragma unroll
        for (int nt = 0; nt < 13; ++nt) {
            int n = nt*16 + ln;
            int row = (n*37450) >> 19;
            int col = n - row*14;
            int pb = (n < 196) ? (row*16 + col) : 0;
            const _Float16* bp = &lin[pb*PSTR + q8];
            #pragma unroll
            for (int ky = 0; ky < 3; ++ky) {
                #pragma unroll
                for (int kx = 0; kx < 3; ++kx) {
                    half8v bv = *(const half8v*)(bp + (ky*16 + kx)*PSTR);
                    acc[nt] = __builtin_amdgcn_mfma_f32_16x16x32_f16(
                        aw[ky*3+kx], bv, acc[nt], 0, 0, 0);
                }
            }
        }
    }

    float4 bi = *(const float4*)&bias[layer*256 + co_w + q*4];
    float bia[4] = {bi.x, bi.y, bi.z, bi.w};
    #pragma unroll
    for (int nt = 0; nt < 13; ++nt) {
        int n = nt*16 + ln;
        if (n < 196) {
            half4v hv;
            #pragma unroll
            for (int i = 0; i < 4; ++i)
                hv[i] = (_Float16)fmaxf(acc[nt][i] + bia[i], 0.f);
            *(half4v*)(outT + ((size_t)r*196 + n)*256 + co_w + q*4) = hv;
        }
    }
}

// ---------------------------------------------------------------------------
// K8: deconv+mask head, fp16 MFMA per-roi GEMM with fused epilogue.
// ---------------------------------------------------------------------------
#define DSTR 264   // LDS act row stride in halves (528 B, 16B-aligned)

template<int NMT>
__device__ __forceinline__ void deconv_pass(
    const _Float16* actL, const _Float16* __restrict__ Wd,
    const float* __restrict__ db, const float* __restrict__ mlw,
    int lab, float (*sred)[4], int wv, int ln, int q, int px0)
{
    float P[NMT][4];
    #pragma unroll
    for (int mt = 0; mt < NMT; ++mt)
        #pragma unroll
        for (int r2 = 0; r2 < 4; ++r2) P[mt][r2] = 0.f;

    for (int c = 0; c < 8; ++c) {
        int n0 = wv*256 + c*32;
        float4v acc[NMT][2];
        #pragma unroll
        for (int mt = 0; mt < NMT; ++mt) {
            acc[mt][0] = (float4v){0.f,0.f,0.f,0.f};
            acc[mt][1] = (float4v){0.f,0.f,0.f,0.f};
        }
        #pragma unroll
        for (int k = 0; k < 8; ++k) {
            const _Float16* wp = Wd + ((size_t)(n0 + ln))*256 + k*32 + q*8;
            half8v b0 = *(const half8v*)wp;
            half8v b1 = *(const half8v*)(wp + 16*256);
            #pragma unroll
            for (int mt = 0; mt < NMT; ++mt) {
                half8v a = *(const half8v*)&actL[(mt*16 + ln)*DSTR + k*32 + q*8];
                acc[mt][0] = __builtin_amdgcn_mfma_f32_16x16x32_f16(
                    a, b0, acc[mt][0], 0, 0, 0);
                acc[mt][1] = __builtin_amdgcn_mfma_f32_16x16x32_f16(
                    a, b1, acc[mt][1], 0, 0, 0);
            }
        }
        #pragma unroll
        for (int j = 0; j < 2; ++j) {
            int n = n0 + j*16 + ln;
            int o = n >> 2;
            float bo = db[o];
            float wl = mlw[lab*256 + o];
            #pragma unroll
            for (int mt = 0; mt < NMT; ++mt)
                #pragma unroll
                for (int r2 = 0; r2 < 4; ++r2)
                    P[mt][r2] += fmaxf(acc[mt][j][r2] + bo, 0.f) * wl;
        }
    }
    #pragma unroll
    for (int mt = 0; mt < NMT; ++mt)
        #pragma unroll
        for (int r2 = 0; r2 < 4; ++r2) {
            float v = P[mt][r2];
            v += __shfl_xor(v, 4);
            v += __shfl_xor(v, 8);
            int px = px0 + mt*16 + q*4 + r2;
            if (ln < 4 && px < 196) atomicAdd(&sred[px][ln], v);
        }
}

__global__ __launch_bounds__(256, 1) void deconv_mask_mfma_kernel(
    const _Float16* __restrict__ mfT, const _Float16* __restrict__ Wd,
    const float* __restrict__ db, const float* __restrict__ mlw,
    const float* __restrict__ mlb, const int* __restrict__ labels,
    float* __restrict__ masks)
{
    __shared__ _Float16 act[112*DSTR];   // 59136 B
    __shared__ float sred[196][4];       //  3136 B
    int t = threadIdx.x;
    int lane = t & 63, wv = t >> 6, ln = lane & 15, q = lane >> 4;
    int mi = blockIdx.x;
    int lab = labels[mi];

    for (int i = t; i < 784; i += 256) ((float*)sred)[i] = 0.f;

    for (int idx = t; idx < 112*32; idx += 256) {
        int px = idx >> 5, g = idx & 31;
        *(float4*)&act[px*DSTR + g*8] =
            *(const float4*)(mfT + ((size_t)mi*196 + px)*256 + g*8);
    }
    __syncthreads();
    deconv_pass<7>(act, Wd, db, mlw, lab, sred, wv, ln, q, 0);
    __syncthreads();

    for (int idx = t; idx < 84*32; idx += 256) {
        int px = idx >> 5, g = idx & 31;
        *(float4*)&act[px*DSTR + g*8] =
            *(const float4*)(mfT + ((size_t)mi*196 + 112 + px)*256 + g*8);
    }
    __syncthreads();
    deconv_pass<6>(act, Wd, db, mlw, lab, sred, wv, ln, q, 112);
    __syncthreads();

    if (t < 196) {
        float bl = mlb[lab];
        int i2 = t / 14, j2 = t % 14;
        #pragma unroll
        for (int pq = 0; pq < 4; ++pq) {
            float s = sred[t][pq] + bl;
            int h = 2*i2 + (pq >> 1), w2 = 2*j2 + (pq & 1);
            masks[(size_t)mi*784 + h*28 + w2] = 1.f/(1.f + expf(-s));
        }
    }
}

// ---------------------------------------------------------------------------
extern "C" void kernel_launch(void* const* d_in, const int* in_sizes, int n_in,
                              void* d_out, int out_size, void* d_ws, size_t ws_size,
                              hipStream_t stream) {
    const float* f0      = (const float*)d_in[0];
    const float* f1      = (const float*)d_in[1];
    const float* f2      = (const float*)d_in[2];
    const float* f3      = (const float*)d_in[3];
    const float* props   = (const float*)d_in[4];
    const float* fc1_w   = (const float*)d_in[5];
    const float* fc1_b   = (const float*)d_in[6];
    const float* fc2_w   = (const float*)d_in[7];
    const float* fc2_b   = (const float*)d_in[8];
    const float* cls_w   = (const float*)d_in[9];
    const float* cls_b   = (const float*)d_in[10];
    const float* bbox_w  = (const float*)d_in[11];
    const float* bbox_b  = (const float*)d_in[12];
    const float* mconv_w = (const float*)d_in[13];
    const float* mconv_b = (const float*)d_in[14];
    const float* dconv_w = (const float*)d_in[15];
    const float* dconv_b = (const float*)d_in[16];
    const float* mlog_w  = (const float*)d_in[17];
    const float* mlog_b  = (const float*)d_in[18];
    const int*   bidx    = (const int*)d_in[19];

    // workspace layout (bytes)
    // fc phase:   bf | x1 | x2 | labels | mboxes | Cp(32MB)
    // mask phase: bufA/bufB alias bf; Wr/Wd alias the (dead) Cp region,
    //             written only after the fc phase completes (stream-ordered).
    char* wsb = (char*)d_ws;
    float*    bf   = (float*)wsb;                    // [0, 51.38MB)
    _Float16* bufA = (_Float16*)wsb;                 // alias: conv ping
    _Float16* bufB = (_Float16*)(wsb + 25690112);    // conv pong
    float*    x1   = (float*)(wsb + 51380224);       // 4MB
    float*    x2   = (float*)(wsb + 55574528);       // 4MB
    int*      labels = (int*)(wsb + 59768832);       // 4KB pad
    float*    mboxes = (float*)(wsb + 59772928);     // 8KB pad
    float*    Cp     = (float*)(wsb + 59781120);     // 32MB (ends ~93.3MB)
    _Float16* Wr     = (_Float16*)(wsb + 59781120);  // alias Cp, 4.72MB
    _Float16* Wd     = (_Float16*)(wsb + 64499712);  // alias Cp, 0.5MB

    float* scores = (float*)d_out;
    float* boxes  = scores + RTOT*NUM_CLASSES;
    float* masks  = boxes + RTOT*NUM_CLASSES*4;

    // K1: roi_align 7x7 -> bf  (channel-split: 4 groups)
    roi_align7_kernel<<<dim3(RTOT, 4), 256, 0, stream>>>(
        f0, f1, f2, f3, props, bidx, bf);

    // K2: fc1 (split-fp16 MFMA, split-K=8 -> 512 blocks, 2/CU) + reduce
    gemm_splitk_f16x3<<<dim3(8, 8, 8), 256, 0, stream>>>(bf, fc1_w, Cp, 12544, 1568);
    fc_reduce_kernel<<<1024, 256, 0, stream>>>(Cp, fc1_b, x1);

    // K3: fc2 (split-K=8, KS=128)
    gemm_splitk_f16x3<<<dim3(8, 8, 8), 256, 0, stream>>>(x1, fc2_w, Cp, 1024, 128);
    fc_reduce_kernel<<<1024, 256, 0, stream>>>(Cp, fc2_b, x2);

    // K4/K5: heads
    cls_head_kernel<<<RTOT, 128, 0, stream>>>(x2, cls_w, cls_b, scores, labels);
    bbox_head_kernel<<<RTOT, 384, 0, stream>>>(x2, bbox_w, bbox_b, props, labels,
                                               boxes, mboxes);

    // W0: weight repacks (after fc phase: Wr/Wd alias the dead Cp region)
    repack_wts_kernel<<<4*9*256, 256, 0, stream>>>(mconv_w, Wr);
    repack_dw_kernel<<<1024, 256, 0, stream>>>(dconv_w, Wd);

    // K6: roi_align 14x14 -> bufA (channel-split: 8 groups)
    roi_align14_kernel<<<dim3(RMASK, 8), 256, 0, stream>>>(
        f0, f1, f2, f3, mboxes, bidx, bufA);

    // K7: 4x conv3x3 MFMA, ping-pong A->B->A->B->A
    conv3x3_mfma_kernel<<<RMASK*4, 256, 0, stream>>>(bufA, Wr, mconv_b, bufB, 0);
    conv3x3_mfma_kernel<<<RMASK*4, 256, 0, stream>>>(bufB, Wr, mconv_b, bufA, 1);
    conv3x3_mfma_kernel<<<RMASK*4, 256, 0, stream>>>(bufA, Wr, mconv_b, bufB, 2);
    conv3x3_mfma_kernel<<<RMASK*4, 256, 0, stream>>>(bufB, Wr, mconv_b, bufA, 3);

    // K8: fused deconv + mask head (MFMA)
    deconv_mask_mfma_kernel<<<RMASK, 256, 0, stream>>>(bufA, Wd, dconv_b, mlog_w,
                                                       mlog_b, labels, masks);
}

// Round 7
// 1221.738 us; speedup vs baseline: 1.0596x; 1.0596x over previous
//
#include <hip/hip_runtime.h>
#include <hip/hip_bf16.h>

// ---------------------------------------------------------------------------
// Mask-RCNN RoI head. Round 6: fc GEMM register-pressure fix.
// R5 post-mortem: 64x64 wave tile = 128 AGPR + 136 VGPR = 264 regs/thread
// > 256 -> 1 wave/SIMD -> 1 block/CU no matter the grid (occupancy pinned
// at 11%). New: 32x64 wave tile (64 AGPR, ~200 total), launch_bounds(256,2),
// block tile 64x128, grid (8,16,4) = 512 blocks = 2 co-resident blocks/CU.
// ---------------------------------------------------------------------------

#define NUM_CLASSES 81
#define CDIM 256
#define RTOT 1024
#define RMASK 256
#define LOG1000_16 4.135166556742356f

typedef _Float16 half8v __attribute__((ext_vector_type(8)));
typedef _Float16 half4v __attribute__((ext_vector_type(4)));
typedef float    float4v __attribute__((ext_vector_type(4)));

// ---------------------------------------------------------------------------
// K1: roi_align out_size=7 -> bf fp32 (1024 x 12544). Block=(roi, 64ch grp).
// ---------------------------------------------------------------------------
__global__ __launch_bounds__(256) void roi_align7_kernel(
    const float* __restrict__ f0, const float* __restrict__ f1,
    const float* __restrict__ f2, const float* __restrict__ f3,
    const float* __restrict__ props, const int* __restrict__ bidx,
    float* __restrict__ bf)
{
    int r  = blockIdx.x;
    int cg = blockIdx.y;          // 4 groups of 64 channels
    int t = threadIdx.x;
    if (t >= 196) return;
    int p  = t % 49;
    int cl = t / 49;              // 4 channel lanes
    int oy = p / 7, ox = p % 7;

    float x1 = props[r*4+0], y1 = props[r*4+1];
    float x2 = props[r*4+2], y2 = props[r*4+3];
    float area = fmaxf(x2-x1, 0.f) * fmaxf(y2-y1, 0.f);
    float lf = floorf(4.f + log2f(sqrtf(area)/224.f + 1e-6f));
    lf = fminf(fmaxf(lf, 2.f), 5.f);
    int lvl = (int)lf - 2;

    const float* feat; int H, W; float scale;
    if (lvl == 0)      { feat = f0; H = 200; W = 200; scale = 0.25f; }
    else if (lvl == 1) { feat = f1; H = 100; W = 100; scale = 0.125f; }
    else if (lvl == 2) { feat = f2; H = 50;  W = 50;  scale = 0.0625f; }
    else               { feat = f3; H = 25;  W = 25;  scale = 0.03125f; }
    int b = bidx[r];

    float x1s = x1*scale, y1s = y1*scale;
    float rw = fmaxf(x2*scale - x1s, 1.f);
    float rh = fmaxf(y2*scale - y1s, 1.f);

    int   offs[4];
    float w00[4], w01[4], w10[4], w11[4];
    #pragma unroll
    for (int sy = 0; sy < 2; ++sy) {
        int iy = oy*2 + sy;
        float gy = ((float)iy + 0.5f) / 14.f;
        float yc = y1s + rh*gy;
        bool  yv = (yc > -1.f) && (yc < (float)H);
        float ycl = fminf(fmaxf(yc, 0.f), (float)(H-1));
        int   y0  = (int)fminf(floorf(ycl), (float)(H-2));
        float ly  = ycl - (float)y0;
        #pragma unroll
        for (int sx = 0; sx < 2; ++sx) {
            int ix = ox*2 + sx;
            float gx = ((float)ix + 0.5f) / 14.f;
            float xc = x1s + rw*gx;
            bool  xv = (xc > -1.f) && (xc < (float)W);
            float xcl = fminf(fmaxf(xc, 0.f), (float)(W-1));
            int   x0  = (int)fminf(floorf(xcl), (float)(W-2));
            float lx  = xcl - (float)x0;
            float m = (yv && xv) ? 1.f : 0.f;
            int s = sy*2 + sx;
            offs[s] = y0*W + x0;
            w00[s] = (1.f-ly)*(1.f-lx)*m;
            w01[s] = (1.f-ly)*lx*m;
            w10[s] = ly*(1.f-lx)*m;
            w11[s] = ly*lx*m;
        }
    }

    size_t HW = (size_t)H * W;
    #pragma unroll 4
    for (int k = 0; k < 16; ++k) {
        int c = cg*64 + cl + k*4;
        const float* fb = feat + ((size_t)b*CDIM + c) * HW;
        float acc = 0.f;
        #pragma unroll
        for (int s = 0; s < 4; ++s) {
            const float* q = fb + offs[s];
            acc += w00[s]*q[0] + w01[s]*q[1] + w10[s]*q[W] + w11[s]*q[W+1];
        }
        bf[(size_t)r*12544 + c*49 + p] = acc * 0.25f;
    }
}

// ---------------------------------------------------------------------------
// K2/K3: split-fp16 MFMA GEMM, partials: Cp[kz][1024][1024].
// Block tile 64(M) x 128(N), 4 waves of 32x64. grid (8, 16, KZ).
// 64 AGPR + ~136 VGPR <= 256 -> 2 waves/SIMD (launch_bounds(256,2)).
// ---------------------------------------------------------------------------
#define FSTR 40

__global__ __launch_bounds__(256, 2) void gemm_splitk_f16x3(
    const float* __restrict__ A, const float* __restrict__ B,
    float* __restrict__ Cp, int K, int KS)
{
    __shared__ _Float16 Ah[64*FSTR];
    __shared__ _Float16 Al[64*FSTR];
    __shared__ _Float16 Bh[128*FSTR];
    __shared__ _Float16 Bl[128*FSTR];

    int t = threadIdx.x;
    int lane = t & 63, wave = t >> 6;
    int wm = wave >> 1, wn = wave & 1;
    int ln = lane & 15, q = lane >> 4;
    int bn = blockIdx.x, bm = blockIdx.y, kz = blockIdx.z;

    const float* Abase = A + (size_t)(bm*64)*K + (size_t)kz*KS;
    const float* Bbase = B + (size_t)(bn*128)*K + (size_t)kz*KS;

    float4v acc1[2][4], acc2[2][4];
    #pragma unroll
    for (int i = 0; i < 2; ++i)
        #pragma unroll
        for (int j = 0; j < 4; ++j) {
            acc1[i][j] = (float4v){0.f,0.f,0.f,0.f};
            acc2[i][j] = (float4v){0.f,0.f,0.f,0.f};
        }

    for (int k0 = 0; k0 < KS; k0 += 32) {
        __syncthreads();
        // stage A: 64 rows x 32 cols, 1 item/thread
        {
            int row = t >> 2, c8 = (t & 3) * 8;
            const float* pa = Abase + (size_t)row*K + k0 + c8;
            float4 v0 = *(const float4*)pa;
            float4 v1 = *(const float4*)(pa + 4);
            float vv[8] = {v0.x,v0.y,v0.z,v0.w,v1.x,v1.y,v1.z,v1.w};
            half8v h, l;
            #pragma unroll
            for (int j = 0; j < 8; ++j) {
                _Float16 hj = (_Float16)vv[j];
                h[j] = hj;
                l[j] = (_Float16)((vv[j] - (float)hj) * 2048.f);
            }
            *(half8v*)&Ah[row*FSTR + c8] = h;
            *(half8v*)&Al[row*FSTR + c8] = l;
        }
        // stage B: 128 rows x 32 cols, 2 items/thread
        #pragma unroll
        for (int it = 0; it < 2; ++it) {
            int idx = it*256 + t;
            int row = idx >> 2, c8 = (idx & 3) * 8;
            const float* pb = Bbase + (size_t)row*K + k0 + c8;
            float4 v0 = *(const float4*)pb;
            float4 v1 = *(const float4*)(pb + 4);
            float vv[8] = {v0.x,v0.y,v0.z,v0.w,v1.x,v1.y,v1.z,v1.w};
            half8v h, l;
            #pragma unroll
            for (int j = 0; j < 8; ++j) {
                _Float16 hj = (_Float16)vv[j];
                h[j] = hj;
                l[j] = (_Float16)((vv[j] - (float)hj) * 2048.f);
            }
            *(half8v*)&Bh[row*FSTR + c8] = h;
            *(half8v*)&Bl[row*FSTR + c8] = l;
        }
        __syncthreads();

        half8v afh[2], afl[2], bfh[4], bfl[4];
        #pragma unroll
        for (int i = 0; i < 2; ++i) {
            int ra = (wm*32 + i*16 + ln)*FSTR + q*8;
            afh[i] = *(const half8v*)&Ah[ra];
            afl[i] = *(const half8v*)&Al[ra];
        }
        #pragma unroll
        for (int j = 0; j < 4; ++j) {
            int rb = (wn*64 + j*16 + ln)*FSTR + q*8;
            bfh[j] = *(const half8v*)&Bh[rb];
            bfl[j] = *(const half8v*)&Bl[rb];
        }
        #pragma unroll
        for (int i = 0; i < 2; ++i) {
            #pragma unroll
            for (int j = 0; j < 4; ++j) {
                acc1[i][j] = __builtin_amdgcn_mfma_f32_16x16x32_f16(
                    afh[i], bfh[j], acc1[i][j], 0, 0, 0);
                acc2[i][j] = __builtin_amdgcn_mfma_f32_16x16x32_f16(
                    afh[i], bfl[j], acc2[i][j], 0, 0, 0);
                acc2[i][j] = __builtin_amdgcn_mfma_f32_16x16x32_f16(
                    afl[i], bfh[j], acc2[i][j], 0, 0, 0);
            }
        }
    }

    float* Cpz = Cp + (size_t)kz*1024*1024;
    #pragma unroll
    for (int i = 0; i < 2; ++i) {
        #pragma unroll
        for (int j = 0; j < 4; ++j) {
            int col = bn*128 + wn*64 + j*16 + ln;
            #pragma unroll
            for (int reg = 0; reg < 4; ++reg) {
                int row = bm*64 + wm*32 + i*16 + q*4 + reg;
                Cpz[(size_t)row*1024 + col] =
                    acc1[i][j][reg] + acc2[i][j][reg] * (1.f/2048.f);
            }
        }
    }
}

// reduce nparts split-K partials + bias + relu -> out (1024x1024 fp32)
__global__ __launch_bounds__(256) void fc_reduce_kernel(
    const float* __restrict__ Cp, const float* __restrict__ bias,
    float* __restrict__ out, int nparts)
{
    int i = blockIdx.x*256 + threadIdx.x;
    const float4* p = (const float4*)Cp;
    float sx = 0.f, sy = 0.f, sz = 0.f, sw = 0.f;
    for (int j = 0; j < nparts; ++j) {
        float4 s = p[i + j*262144];
        sx += s.x; sy += s.y; sz += s.z; sw += s.w;
    }
    float4 b4 = ((const float4*)bias)[i & 255];
    float4 v;
    v.x = fmaxf(sx + b4.x, 0.f);
    v.y = fmaxf(sy + b4.y, 0.f);
    v.z = fmaxf(sz + b4.z, 0.f);
    v.w = fmaxf(sw + b4.w, 0.f);
    ((float4*)out)[i] = v;
}

// ---------------------------------------------------------------------------
// K4: cls head (softmax scores + labels)
// ---------------------------------------------------------------------------
__global__ __launch_bounds__(128) void cls_head_kernel(
    const float* __restrict__ x, const float* __restrict__ w,
    const float* __restrict__ b, float* __restrict__ scores,
    int* __restrict__ labels)
{
    __shared__ float xr[1024];
    __shared__ float lg[NUM_CLASSES];
    __shared__ float red[2];
    int r = blockIdx.x, t = threadIdx.x;
    const float4* xp = (const float4*)(x + (size_t)r*1024);
    float4* xr4 = (float4*)xr;
    for (int i = t; i < 256; i += 128) xr4[i] = xp[i];
    __syncthreads();
    if (t < NUM_CLASSES) {
        const float* wr = w + (size_t)t*1024;
        float acc = b[t];
        for (int k = 0; k < 1024; k += 4)
            acc += xr[k]*wr[k] + xr[k+1]*wr[k+1] + xr[k+2]*wr[k+2] + xr[k+3]*wr[k+3];
        lg[t] = acc;
    }
    __syncthreads();
    if (t == 0) {
        float mx = lg[0];
        for (int j = 1; j < NUM_CLASSES; ++j) mx = fmaxf(mx, lg[j]);
        red[0] = mx;
    }
    __syncthreads();
    float mx = red[0];
    if (t < NUM_CLASSES) lg[t] = expf(lg[t] - mx);
    __syncthreads();
    if (t == 0) {
        float s = 0.f;
        for (int j = 0; j < NUM_CLASSES; ++j) s += lg[j];
        red[1] = 1.f/s;
    }
    __syncthreads();
    if (t < NUM_CLASSES) scores[(size_t)r*NUM_CLASSES + t] = lg[t]*red[1];
    if (t == 0) {
        bool sel = (r < 128) || (r >= 512 && r < 640);
        if (sel) {
            int mi = (r < 128) ? r : r - 384;
            int best = 1; float bv = lg[1];
            for (int j = 2; j < NUM_CLASSES; ++j)
                if (lg[j] > bv) { bv = lg[j]; best = j; }
            labels[mi] = best;
        }
    }
}

// ---------------------------------------------------------------------------
// K5: bbox head (decode boxes + mboxes)
// ---------------------------------------------------------------------------
__global__ __launch_bounds__(384) void bbox_head_kernel(
    const float* __restrict__ x, const float* __restrict__ w,
    const float* __restrict__ bias, const float* __restrict__ props,
    const int* __restrict__ labels, float* __restrict__ boxes,
    float* __restrict__ mboxes)
{
    __shared__ float xr[1024];
    __shared__ float dl[NUM_CLASSES*4];
    int r = blockIdx.x, t = threadIdx.x;
    for (int i = t; i < 1024; i += 384) xr[i] = x[(size_t)r*1024 + i];
    __syncthreads();
    if (t < NUM_CLASSES*4) {
        const float* wr = w + (size_t)t*1024;
        float acc = bias[t];
        for (int k = 0; k < 1024; k += 4)
            acc += xr[k]*wr[k] + xr[k+1]*wr[k+1] + xr[k+2]*wr[k+2] + xr[k+3]*wr[k+3];
        dl[t] = acc;
    }
    __syncthreads();
    if (t < NUM_CLASSES) {
        float px1 = props[r*4+0], py1 = props[r*4+1];
        float px2 = props[r*4+2], py2 = props[r*4+3];
        float pw = px2 - px1, ph = py2 - py1;
        float cx = px1 + 0.5f*pw, cy = py1 + 0.5f*ph;
        float d0 = dl[t*4+0] * 0.1f;
        float d1 = dl[t*4+1] * 0.1f;
        float d2 = fminf(dl[t*4+2] * 0.2f, LOG1000_16);
        float d3 = fminf(dl[t*4+3] * 0.2f, LOG1000_16);
        float pcx = d0*pw + cx, pcy = d1*ph + cy;
        float qw = expf(d2)*pw, qh = expf(d3)*ph;
        float b0 = fminf(fmaxf(pcx - 0.5f*qw, 0.f), 800.f);
        float b1 = fminf(fmaxf(pcy - 0.5f*qh, 0.f), 800.f);
        float b2 = fminf(fmaxf(pcx + 0.5f*qw, 0.f), 800.f);
        float b3 = fminf(fmaxf(pcy + 0.5f*qh, 0.f), 800.f);
        size_t ob = ((size_t)r*NUM_CLASSES + t)*4;
        boxes[ob+0] = b0; boxes[ob+1] = b1; boxes[ob+2] = b2; boxes[ob+3] = b3;
        bool sel = (r < 128) || (r >= 512 && r < 640);
        if (sel) {
            int mi = (r < 128) ? r : r - 384;
            if (labels[mi] == t) {
                mboxes[mi*4+0] = b0; mboxes[mi*4+1] = b1;
                mboxes[mi*4+2] = b2; mboxes[mi*4+3] = b3;
            }
        }
    }
}

// ---------------------------------------------------------------------------
// K6: roi_align 14x14 -> transposed fp16 actT[mi][p][c]. Block=(roi,32ch grp).
// ---------------------------------------------------------------------------
__global__ __launch_bounds__(256) void roi_align14_kernel(
    const float* __restrict__ f0, const float* __restrict__ f1,
    const float* __restrict__ f2, const float* __restrict__ f3,
    const float* __restrict__ mboxes, const int* __restrict__ bidx,
    _Float16* __restrict__ outT)
{
    int mi = blockIdx.x;
    int cg = blockIdx.y;          // 8 groups of 32 channels
    int t = threadIdx.x;
    if (t >= 196) return;
    int oy = t / 14, ox = t % 14;

    float x1 = mboxes[mi*4+0], y1 = mboxes[mi*4+1];
    float x2 = mboxes[mi*4+2], y2 = mboxes[mi*4+3];
    float area = fmaxf(x2-x1, 0.f) * fmaxf(y2-y1, 0.f);
    float lf = floorf(4.f + log2f(sqrtf(area)/224.f + 1e-6f));
    lf = fminf(fmaxf(lf, 2.f), 5.f);
    int lvl = (int)lf - 2;

    const float* feat; int H, W; float scale;
    if (lvl == 0)      { feat = f0; H = 200; W = 200; scale = 0.25f; }
    else if (lvl == 1) { feat = f1; H = 100; W = 100; scale = 0.125f; }
    else if (lvl == 2) { feat = f2; H = 50;  W = 50;  scale = 0.0625f; }
    else               { feat = f3; H = 25;  W = 25;  scale = 0.03125f; }
    int ridx = (mi < 128) ? mi : mi + 384;
    int b = bidx[ridx];

    float x1s = x1*scale, y1s = y1*scale;
    float rw = fmaxf(x2*scale - x1s, 1.f);
    float rh = fmaxf(y2*scale - y1s, 1.f);

    int   offs[4];
    float w00[4], w01[4], w10[4], w11[4];
    #pragma unroll
    for (int sy = 0; sy < 2; ++sy) {
        int iy = oy*2 + sy;
        float gy = ((float)iy + 0.5f) / 28.f;
        float yc = y1s + rh*gy;
        bool  yv = (yc > -1.f) && (yc < (float)H);
        float ycl = fminf(fmaxf(yc, 0.f), (float)(H-1));
        int   y0  = (int)fminf(floorf(ycl), (float)(H-2));
        float ly  = ycl - (float)y0;
        #pragma unroll
        for (int sx = 0; sx < 2; ++sx) {
            int ix = ox*2 + sx;
            float gx = ((float)ix + 0.5f) / 28.f;
            float xc = x1s + rw*gx;
            bool  xv = (xc > -1.f) && (xc < (float)W);
            float xcl = fminf(fmaxf(xc, 0.f), (float)(W-1));
            int   x0  = (int)fminf(floorf(xcl), (float)(W-2));
            float lx  = xcl - (float)x0;
            float m = (yv && xv) ? 1.f : 0.f;
            int s = sy*2 + sx;
            offs[s] = y0*W + x0;
            w00[s] = (1.f-ly)*(1.f-lx)*m;
            w01[s] = (1.f-ly)*lx*m;
            w10[s] = ly*(1.f-lx)*m;
            w11[s] = ly*lx*m;
        }
    }

    size_t HW = (size_t)H * W;
    _Float16* orow = outT + ((size_t)mi*196 + t)*CDIM + cg*32;
    const float* fbase = feat + ((size_t)b*CDIM + cg*32) * HW;
    #pragma unroll
    for (int c8 = 0; c8 < 32; c8 += 8) {
        half8v hv;
        #pragma unroll
        for (int cc = 0; cc < 8; ++cc) {
            const float* fb = fbase + (size_t)(c8+cc) * HW;
            float acc = 0.f;
            #pragma unroll
            for (int s = 0; s < 4; ++s) {
                const float* q = fb + offs[s];
                acc += w00[s]*q[0] + w01[s]*q[1] + w10[s]*q[W] + w11[s]*q[W+1];
            }
            hv[cc] = (_Float16)(acc * 0.25f);
        }
        *(half8v*)(orow + c8) = hv;
    }
}

// ---------------------------------------------------------------------------
// Weight repacks
// ---------------------------------------------------------------------------
__global__ __launch_bounds__(256) void repack_wts_kernel(
    const float* __restrict__ w, _Float16* __restrict__ Wr)
{
    int i = blockIdx.x*256 + threadIdx.x;   // 4*9*256*256
    int ci = i & 255;
    int rest = i >> 8;
    int co = rest & 255;
    int rest2 = rest >> 8;
    int tap = rest2 % 9;
    int l = rest2 / 9;
    Wr[i] = (_Float16)w[(((size_t)(l*256 + co)*256 + ci)*9) + tap];
}

// deconv_w[c][o][p][q] fp32 -> Wd[n=o*4+p*2+q][c] fp16  (pure transpose)
__global__ __launch_bounds__(256) void repack_dw_kernel(
    const float* __restrict__ dw, _Float16* __restrict__ Wd)
{
    int i = blockIdx.x*256 + threadIdx.x;   // 1024*256
    int n = i >> 8, k = i & 255;
    Wd[i] = (_Float16)dw[(size_t)k*1024 + n];
}

// ---------------------------------------------------------------------------
// K7: conv3x3+bias+relu as fp16 MFMA implicit GEMM.
// ---------------------------------------------------------------------------
#define PSTR 40

__global__ __launch_bounds__(256) void conv3x3_mfma_kernel(
    const _Float16* __restrict__ inT, const _Float16* __restrict__ Wr,
    const float* __restrict__ bias, _Float16* __restrict__ outT, int layer)
{
    __shared__ _Float16 lin[256*PSTR];   // 20 KiB

    int t = threadIdx.x;
    int lane = t & 63;
    int wave = t >> 6;
    int ln = lane & 15;
    int q  = lane >> 4;
    int q8 = q*8;
    int r  = blockIdx.x >> 2;
    int bc = blockIdx.x & 3;
    int co_w = bc*64 + wave*16;

    const _Float16* WrL = Wr + (size_t)layer*9*256*256;
    const _Float16* inR = inT + (size_t)r*196*256;

    for (int i = t; i < 256*PSTR; i += 256) lin[i] = (_Float16)0.f;

    float4v acc[13];
    #pragma unroll
    for (int nt = 0; nt < 13; ++nt) acc[nt] = (float4v){0.f,0.f,0.f,0.f};

    for (int ci0 = 0; ci0 < 256; ci0 += 32) {
        __syncthreads();
        for (int idx = t; idx < 784; idx += 256) {
            int p = idx >> 2, g = idx & 3;
            float4 v = *(const float4*)(inR + (size_t)p*256 + ci0 + g*8);
            int row = (p*37450) >> 19;
            int col = p - row*14;
            *(float4*)&lin[((row+1)*16 + (col+1))*PSTR + g*8] = v;
        }
        __syncthreads();

        half8v aw[9];
        #pragma unroll
        for (int tap = 0; tap < 9; ++tap)
            aw[tap] = *(const half8v*)(WrL + ((size_t)tap*256 + co_w + ln)*256 + ci0 + q8);

        #pragma unroll
        for (int nt = 0; nt < 13; ++nt) {
            int n = nt*16 + ln;
            int row = (n*37450) >> 19;
            int col = n - row*14;
            int pb = (n < 196) ? (row*16 + col) : 0;
            const _Float16* bp = &lin[pb*PSTR + q8];
            #pragma unroll
            for (int ky = 0; ky < 3; ++ky) {
                #pragma unroll
                for (int kx = 0; kx < 3; ++kx) {
                    half8v bv = *(const half8v*)(bp + (ky*16 + kx)*PSTR);
                    acc[nt] = __builtin_amdgcn_mfma_f32_16x16x32_f16(
                        aw[ky*3+kx], bv, acc[nt], 0, 0, 0);
                }
            }
        }
    }

    float4 bi = *(const float4*)&bias[layer*256 + co_w + q*4];
    float bia[4] = {bi.x, bi.y, bi.z, bi.w};
    #pragma unroll
    for (int nt = 0; nt < 13; ++nt) {
        int n = nt*16 + ln;
        if (n < 196) {
            half4v hv;
            #pragma unroll
            for (int i = 0; i < 4; ++i)
                hv[i] = (_Float16)fmaxf(acc[nt][i] + bia[i], 0.f);
            *(half4v*)(outT + ((size_t)r*196 + n)*256 + co_w + q*4) = hv;
        }
    }
}

// ---------------------------------------------------------------------------
// K8: deconv+mask head, fp16 MFMA per-roi GEMM with fused epilogue.
// ---------------------------------------------------------------------------
#define DSTR 264   // LDS act row stride in halves (528 B, 16B-aligned)

template<int NMT>
__device__ __forceinline__ void deconv_pass(
    const _Float16* actL, const _Float16* __restrict__ Wd,
    const float* __restrict__ db, const float* __restrict__ mlw,
    int lab, float (*sred)[4], int wv, int ln, int q, int px0)
{
    float P[NMT][4];
    #pragma unroll
    for (int mt = 0; mt < NMT; ++mt)
        #pragma unroll
        for (int r2 = 0; r2 < 4; ++r2) P[mt][r2] = 0.f;

    for (int c = 0; c < 8; ++c) {
        int n0 = wv*256 + c*32;
        float4v acc[NMT][2];
        #pragma unroll
        for (int mt = 0; mt < NMT; ++mt) {
            acc[mt][0] = (float4v){0.f,0.f,0.f,0.f};
            acc[mt][1] = (float4v){0.f,0.f,0.f,0.f};
        }
        #pragma unroll
        for (int k = 0; k < 8; ++k) {
            const _Float16* wp = Wd + ((size_t)(n0 + ln))*256 + k*32 + q*8;
            half8v b0 = *(const half8v*)wp;
            half8v b1 = *(const half8v*)(wp + 16*256);
            #pragma unroll
            for (int mt = 0; mt < NMT; ++mt) {
                half8v a = *(const half8v*)&actL[(mt*16 + ln)*DSTR + k*32 + q*8];
                acc[mt][0] = __builtin_amdgcn_mfma_f32_16x16x32_f16(
                    a, b0, acc[mt][0], 0, 0, 0);
                acc[mt][1] = __builtin_amdgcn_mfma_f32_16x16x32_f16(
                    a, b1, acc[mt][1], 0, 0, 0);
            }
        }
        #pragma unroll
        for (int j = 0; j < 2; ++j) {
            int n = n0 + j*16 + ln;
            int o = n >> 2;
            float bo = db[o];
            float wl = mlw[lab*256 + o];
            #pragma unroll
            for (int mt = 0; mt < NMT; ++mt)
                #pragma unroll
                for (int r2 = 0; r2 < 4; ++r2)
                    P[mt][r2] += fmaxf(acc[mt][j][r2] + bo, 0.f) * wl;
        }
    }
    #pragma unroll
    for (int mt = 0; mt < NMT; ++mt)
        #pragma unroll
        for (int r2 = 0; r2 < 4; ++r2) {
            float v = P[mt][r2];
            v += __shfl_xor(v, 4);
            v += __shfl_xor(v, 8);
            int px = px0 + mt*16 + q*4 + r2;
            if (ln < 4 && px < 196) atomicAdd(&sred[px][ln], v);
        }
}

__global__ __launch_bounds__(256, 1) void deconv_mask_mfma_kernel(
    const _Float16* __restrict__ mfT, const _Float16* __restrict__ Wd,
    const float* __restrict__ db, const float* __restrict__ mlw,
    const float* __restrict__ mlb, const int* __restrict__ labels,
    float* __restrict__ masks)
{
    __shared__ _Float16 act[112*DSTR];   // 59136 B
    __shared__ float sred[196][4];       //  3136 B
    int t = threadIdx.x;
    int lane = t & 63, wv = t >> 6, ln = lane & 15, q = lane >> 4;
    int mi = blockIdx.x;
    int lab = labels[mi];

    for (int i = t; i < 784; i += 256) ((float*)sred)[i] = 0.f;

    for (int idx = t; idx < 112*32; idx += 256) {
        int px = idx >> 5, g = idx & 31;
        *(float4*)&act[px*DSTR + g*8] =
            *(const float4*)(mfT + ((size_t)mi*196 + px)*256 + g*8);
    }
    __syncthreads();
    deconv_pass<7>(act, Wd, db, mlw, lab, sred, wv, ln, q, 0);
    __syncthreads();

    for (int idx = t; idx < 84*32; idx += 256) {
        int px = idx >> 5, g = idx & 31;
        *(float4*)&act[px*DSTR + g*8] =
            *(const float4*)(mfT + ((size_t)mi*196 + 112 + px)*256 + g*8);
    }
    __syncthreads();
    deconv_pass<6>(act, Wd, db, mlw, lab, sred, wv, ln, q, 112);
    __syncthreads();

    if (t < 196) {
        float bl = mlb[lab];
        int i2 = t / 14, j2 = t % 14;
        #pragma unroll
        for (int pq = 0; pq < 4; ++pq) {
            float s = sred[t][pq] + bl;
            int h = 2*i2 + (pq >> 1), w2 = 2*j2 + (pq & 1);
            masks[(size_t)mi*784 + h*28 + w2] = 1.f/(1.f + expf(-s));
        }
    }
}

// ---------------------------------------------------------------------------
extern "C" void kernel_launch(void* const* d_in, const int* in_sizes, int n_in,
                              void* d_out, int out_size, void* d_ws, size_t ws_size,
                              hipStream_t stream) {
    const float* f0      = (const float*)d_in[0];
    const float* f1      = (const float*)d_in[1];
    const float* f2      = (const float*)d_in[2];
    const float* f3      = (const float*)d_in[3];
    const float* props   = (const float*)d_in[4];
    const float* fc1_w   = (const float*)d_in[5];
    const float* fc1_b   = (const float*)d_in[6];
    const float* fc2_w   = (const float*)d_in[7];
    const float* fc2_b   = (const float*)d_in[8];
    const float* cls_w   = (const float*)d_in[9];
    const float* cls_b   = (const float*)d_in[10];
    const float* bbox_w  = (const float*)d_in[11];
    const float* bbox_b  = (const float*)d_in[12];
    const float* mconv_w = (const float*)d_in[13];
    const float* mconv_b = (const float*)d_in[14];
    const float* dconv_w = (const float*)d_in[15];
    const float* dconv_b = (const float*)d_in[16];
    const float* mlog_w  = (const float*)d_in[17];
    const float* mlog_b  = (const float*)d_in[18];
    const int*   bidx    = (const int*)d_in[19];

    // workspace layout (bytes)
    char* wsb = (char*)d_ws;
    float*    bf   = (float*)wsb;                    // [0, 51.38MB)
    _Float16* bufA = (_Float16*)wsb;                 // alias: conv ping
    _Float16* bufB = (_Float16*)(wsb + 25690112);    // conv pong
    float*    x1   = (float*)(wsb + 51380224);       // 4MB
    float*    x2   = (float*)(wsb + 55574528);       // 4MB
    int*      labels = (int*)(wsb + 59768832);       // 4KB pad
    float*    mboxes = (float*)(wsb + 59772928);     // 8KB pad
    float*    Cp     = (float*)(wsb + 59781120);     // 16MB split-K partials
    _Float16* Wr     = (_Float16*)(wsb + 59781120);  // alias Cp (after fc)
    _Float16* Wd     = (_Float16*)(wsb + 64499712);  // alias Cp (after fc)

    float* scores = (float*)d_out;
    float* boxes  = scores + RTOT*NUM_CLASSES;
    float* masks  = boxes + RTOT*NUM_CLASSES*4;

    // K1: roi_align 7x7 -> bf  (channel-split: 4 groups)
    roi_align7_kernel<<<dim3(RTOT, 4), 256, 0, stream>>>(
        f0, f1, f2, f3, props, bidx, bf);

    // K2: fc1 (split-fp16 MFMA, block 64x128, split-K=4 -> 512 blocks)
    gemm_splitk_f16x3<<<dim3(8, 16, 4), 256, 0, stream>>>(bf, fc1_w, Cp, 12544, 3136);
    fc_reduce_kernel<<<1024, 256, 0, stream>>>(Cp, fc1_b, x1, 4);

    // K3: fc2 (split-K=4, KS=256)
    gemm_splitk_f16x3<<<dim3(8, 16, 4), 256, 0, stream>>>(x1, fc2_w, Cp, 1024, 256);
    fc_reduce_kernel<<<1024, 256, 0, stream>>>(Cp, fc2_b, x2, 4);

    // K4/K5: heads
    cls_head_kernel<<<RTOT, 128, 0, stream>>>(x2, cls_w, cls_b, scores, labels);
    bbox_head_kernel<<<RTOT, 384, 0, stream>>>(x2, bbox_w, bbox_b, props, labels,
                                               boxes, mboxes);

    // W0: weight repacks (after fc phase: Wr/Wd alias the dead Cp region)
    repack_wts_kernel<<<4*9*256, 256, 0, stream>>>(mconv_w, Wr);
    repack_dw_kernel<<<1024, 256, 0, stream>>>(dconv_w, Wd);

    // K6: roi_align 14x14 -> bufA (channel-split: 8 groups)
    roi_align14_kernel<<<dim3(RMASK, 8), 256, 0, stream>>>(
        f0, f1, f2, f3, mboxes, bidx, bufA);

    // K7: 4x conv3x3 MFMA, ping-pong A->B->A->B->A
    conv3x3_mfma_kernel<<<RMASK*4, 256, 0, stream>>>(bufA, Wr, mconv_b, bufB, 0);
    conv3x3_mfma_kernel<<<RMASK*4, 256, 0, stream>>>(bufB, Wr, mconv_b, bufA, 1);
    conv3x3_mfma_kernel<<<RMASK*4, 256, 0, stream>>>(bufA, Wr, mconv_b, bufB, 2);
    conv3x3_mfma_kernel<<<RMASK*4, 256, 0, stream>>>(bufB, Wr, mconv_b, bufA, 3);

    // K8: fused deconv + mask head (MFMA)
    deconv_mask_mfma_kernel<<<RMASK, 256, 0, stream>>>(bufA, Wd, dconv_b, mlog_w,
                                                       mlog_b, labels, masks);
}

// Round 8
// 1047.824 us; speedup vs baseline: 1.2355x; 1.1660x over previous
//
#include <hip/hip_runtime.h>
#include <hip/hip_bf16.h>

// ---------------------------------------------------------------------------
// Mask-RCNN RoI head. Round 7: cls+bbox heads -> one batched MFMA GEMM.
// Old per-roi dot-product kernels (bbox 160us, cls ~60us; latency-bound on
// L2 weight re-reads) replaced by: Wcat(512x1024)=concat(cls_w,bbox_w,pad),
// L = x2 @ Wcat^T via split-fp16 GEMM (N-stride generalized), then a tiny
// heads_finish kernel doing softmax/argmax/decode from precomputed L.
// ---------------------------------------------------------------------------

#define NUM_CLASSES 81
#define CDIM 256
#define RTOT 1024
#define RMASK 256
#define LOG1000_16 4.135166556742356f

typedef _Float16 half8v __attribute__((ext_vector_type(8)));
typedef _Float16 half4v __attribute__((ext_vector_type(4)));
typedef float    float4v __attribute__((ext_vector_type(4)));

// ---------------------------------------------------------------------------
// K1: roi_align out_size=7 -> bf fp32 (1024 x 12544). Block=(roi, 64ch grp).
// ---------------------------------------------------------------------------
__global__ __launch_bounds__(256) void roi_align7_kernel(
    const float* __restrict__ f0, const float* __restrict__ f1,
    const float* __restrict__ f2, const float* __restrict__ f3,
    const float* __restrict__ props, const int* __restrict__ bidx,
    float* __restrict__ bf)
{
    int r  = blockIdx.x;
    int cg = blockIdx.y;          // 4 groups of 64 channels
    int t = threadIdx.x;
    if (t >= 196) return;
    int p  = t % 49;
    int cl = t / 49;              // 4 channel lanes
    int oy = p / 7, ox = p % 7;

    float x1 = props[r*4+0], y1 = props[r*4+1];
    float x2 = props[r*4+2], y2 = props[r*4+3];
    float area = fmaxf(x2-x1, 0.f) * fmaxf(y2-y1, 0.f);
    float lf = floorf(4.f + log2f(sqrtf(area)/224.f + 1e-6f));
    lf = fminf(fmaxf(lf, 2.f), 5.f);
    int lvl = (int)lf - 2;

    const float* feat; int H, W; float scale;
    if (lvl == 0)      { feat = f0; H = 200; W = 200; scale = 0.25f; }
    else if (lvl == 1) { feat = f1; H = 100; W = 100; scale = 0.125f; }
    else if (lvl == 2) { feat = f2; H = 50;  W = 50;  scale = 0.0625f; }
    else               { feat = f3; H = 25;  W = 25;  scale = 0.03125f; }
    int b = bidx[r];

    float x1s = x1*scale, y1s = y1*scale;
    float rw = fmaxf(x2*scale - x1s, 1.f);
    float rh = fmaxf(y2*scale - y1s, 1.f);

    int   offs[4];
    float w00[4], w01[4], w10[4], w11[4];
    #pragma unroll
    for (int sy = 0; sy < 2; ++sy) {
        int iy = oy*2 + sy;
        float gy = ((float)iy + 0.5f) / 14.f;
        float yc = y1s + rh*gy;
        bool  yv = (yc > -1.f) && (yc < (float)H);
        float ycl = fminf(fmaxf(yc, 0.f), (float)(H-1));
        int   y0  = (int)fminf(floorf(ycl), (float)(H-2));
        float ly  = ycl - (float)y0;
        #pragma unroll
        for (int sx = 0; sx < 2; ++sx) {
            int ix = ox*2 + sx;
            float gx = ((float)ix + 0.5f) / 14.f;
            float xc = x1s + rw*gx;
            bool  xv = (xc > -1.f) && (xc < (float)W);
            float xcl = fminf(fmaxf(xc, 0.f), (float)(W-1));
            int   x0  = (int)fminf(floorf(xcl), (float)(W-2));
            float lx  = xcl - (float)x0;
            float m = (yv && xv) ? 1.f : 0.f;
            int s = sy*2 + sx;
            offs[s] = y0*W + x0;
            w00[s] = (1.f-ly)*(1.f-lx)*m;
            w01[s] = (1.f-ly)*lx*m;
            w10[s] = ly*(1.f-lx)*m;
            w11[s] = ly*lx*m;
        }
    }

    size_t HW = (size_t)H * W;
    #pragma unroll 4
    for (int k = 0; k < 16; ++k) {
        int c = cg*64 + cl + k*4;
        const float* fb = feat + ((size_t)b*CDIM + c) * HW;
        float acc = 0.f;
        #pragma unroll
        for (int s = 0; s < 4; ++s) {
            const float* q = fb + offs[s];
            acc += w00[s]*q[0] + w01[s]*q[1] + w10[s]*q[W] + w11[s]*q[W+1];
        }
        bf[(size_t)r*12544 + c*49 + p] = acc * 0.25f;
    }
}

// ---------------------------------------------------------------------------
// K2/K3/heads: split-fp16 MFMA GEMM, partials Cp[kz][1024][NS].
// Block tile 64(M) x 128(N), 4 waves of 32x64. grid (NS/128, 16, KZ).
// ---------------------------------------------------------------------------
#define FSTR 40

__global__ __launch_bounds__(256, 2) void gemm_splitk_f16x3(
    const float* __restrict__ A, const float* __restrict__ B,
    float* __restrict__ Cp, int K, int KS, int NS)
{
    __shared__ _Float16 Ah[64*FSTR];
    __shared__ _Float16 Al[64*FSTR];
    __shared__ _Float16 Bh[128*FSTR];
    __shared__ _Float16 Bl[128*FSTR];

    int t = threadIdx.x;
    int lane = t & 63, wave = t >> 6;
    int wm = wave >> 1, wn = wave & 1;
    int ln = lane & 15, q = lane >> 4;
    int bn = blockIdx.x, bm = blockIdx.y, kz = blockIdx.z;

    const float* Abase = A + (size_t)(bm*64)*K + (size_t)kz*KS;
    const float* Bbase = B + (size_t)(bn*128)*K + (size_t)kz*KS;

    float4v acc1[2][4], acc2[2][4];
    #pragma unroll
    for (int i = 0; i < 2; ++i)
        #pragma unroll
        for (int j = 0; j < 4; ++j) {
            acc1[i][j] = (float4v){0.f,0.f,0.f,0.f};
            acc2[i][j] = (float4v){0.f,0.f,0.f,0.f};
        }

    for (int k0 = 0; k0 < KS; k0 += 32) {
        __syncthreads();
        // stage A: 64 rows x 32 cols, 1 item/thread
        {
            int row = t >> 2, c8 = (t & 3) * 8;
            const float* pa = Abase + (size_t)row*K + k0 + c8;
            float4 v0 = *(const float4*)pa;
            float4 v1 = *(const float4*)(pa + 4);
            float vv[8] = {v0.x,v0.y,v0.z,v0.w,v1.x,v1.y,v1.z,v1.w};
            half8v h, l;
            #pragma unroll
            for (int j = 0; j < 8; ++j) {
                _Float16 hj = (_Float16)vv[j];
                h[j] = hj;
                l[j] = (_Float16)((vv[j] - (float)hj) * 2048.f);
            }
            *(half8v*)&Ah[row*FSTR + c8] = h;
            *(half8v*)&Al[row*FSTR + c8] = l;
        }
        // stage B: 128 rows x 32 cols, 2 items/thread
        #pragma unroll
        for (int it = 0; it < 2; ++it) {
            int idx = it*256 + t;
            int row = idx >> 2, c8 = (idx & 3) * 8;
            const float* pb = Bbase + (size_t)row*K + k0 + c8;
            float4 v0 = *(const float4*)pb;
            float4 v1 = *(const float4*)(pb + 4);
            float vv[8] = {v0.x,v0.y,v0.z,v0.w,v1.x,v1.y,v1.z,v1.w};
            half8v h, l;
            #pragma unroll
            for (int j = 0; j < 8; ++j) {
                _Float16 hj = (_Float16)vv[j];
                h[j] = hj;
                l[j] = (_Float16)((vv[j] - (float)hj) * 2048.f);
            }
            *(half8v*)&Bh[row*FSTR + c8] = h;
            *(half8v*)&Bl[row*FSTR + c8] = l;
        }
        __syncthreads();

        half8v afh[2], afl[2], bfh[4], bfl[4];
        #pragma unroll
        for (int i = 0; i < 2; ++i) {
            int ra = (wm*32 + i*16 + ln)*FSTR + q*8;
            afh[i] = *(const half8v*)&Ah[ra];
            afl[i] = *(const half8v*)&Al[ra];
        }
        #pragma unroll
        for (int j = 0; j < 4; ++j) {
            int rb = (wn*64 + j*16 + ln)*FSTR + q*8;
            bfh[j] = *(const half8v*)&Bh[rb];
            bfl[j] = *(const half8v*)&Bl[rb];
        }
        #pragma unroll
        for (int i = 0; i < 2; ++i) {
            #pragma unroll
            for (int j = 0; j < 4; ++j) {
                acc1[i][j] = __builtin_amdgcn_mfma_f32_16x16x32_f16(
                    afh[i], bfh[j], acc1[i][j], 0, 0, 0);
                acc2[i][j] = __builtin_amdgcn_mfma_f32_16x16x32_f16(
                    afh[i], bfl[j], acc2[i][j], 0, 0, 0);
                acc2[i][j] = __builtin_amdgcn_mfma_f32_16x16x32_f16(
                    afl[i], bfh[j], acc2[i][j], 0, 0, 0);
            }
        }
    }

    float* Cpz = Cp + (size_t)kz*1024*NS;
    #pragma unroll
    for (int i = 0; i < 2; ++i) {
        #pragma unroll
        for (int j = 0; j < 4; ++j) {
            int col = bn*128 + wn*64 + j*16 + ln;
            #pragma unroll
            for (int reg = 0; reg < 4; ++reg) {
                int row = bm*64 + wm*32 + i*16 + q*4 + reg;
                Cpz[(size_t)row*NS + col] =
                    acc1[i][j][reg] + acc2[i][j][reg] * (1.f/2048.f);
            }
        }
    }
}

// reduce nparts split-K partials + bias (+optional relu) -> out (1024xNS fp32)
// ns4 = NS/4 (power of two). grid = 1024*ns4/256 blocks.
__global__ __launch_bounds__(256) void fc_reduce_kernel(
    const float* __restrict__ Cp, const float* __restrict__ bias,
    float* __restrict__ out, int nparts, int ns4, int do_relu)
{
    int i = blockIdx.x*256 + threadIdx.x;
    const float4* p = (const float4*)Cp;
    int pstride = 1024*ns4;
    float sx = 0.f, sy = 0.f, sz = 0.f, sw = 0.f;
    for (int j = 0; j < nparts; ++j) {
        float4 s = p[i + j*pstride];
        sx += s.x; sy += s.y; sz += s.z; sw += s.w;
    }
    float4 b4 = ((const float4*)bias)[i & (ns4-1)];
    float4 v;
    v.x = sx + b4.x; v.y = sy + b4.y; v.z = sz + b4.z; v.w = sw + b4.w;
    if (do_relu) {
        v.x = fmaxf(v.x, 0.f); v.y = fmaxf(v.y, 0.f);
        v.z = fmaxf(v.z, 0.f); v.w = fmaxf(v.w, 0.f);
    }
    ((float4*)out)[i] = v;
}

// ---------------------------------------------------------------------------
// Head weight concat: Wcat[512][1024] = [cls_w(81); bbox_w(324); 0-pad],
// bcat[512] likewise.
// ---------------------------------------------------------------------------
__global__ __launch_bounds__(256) void repack_head_kernel(
    const float* __restrict__ cls_w, const float* __restrict__ cls_b,
    const float* __restrict__ bbox_w, const float* __restrict__ bbox_b,
    float* __restrict__ Wcat, float* __restrict__ bcat)
{
    int i = blockIdx.x*256 + threadIdx.x;    // 512*1024
    int row = i >> 10, col = i & 1023;
    float v = 0.f;
    if (row < 81) v = cls_w[row*1024 + col];
    else if (row < 405) v = bbox_w[(row-81)*1024 + col];
    Wcat[i] = v;
    if (i < 512) {
        float bv = 0.f;
        if (i < 81) bv = cls_b[i];
        else if (i < 405) bv = bbox_b[i-81];
        bcat[i] = bv;
    }
}

// ---------------------------------------------------------------------------
// heads_finish: per roi, softmax(logits)->scores, argmax->labels,
// decode(deltas)->boxes + mboxes. Reads precomputed L[1024][512].
// ---------------------------------------------------------------------------
__global__ __launch_bounds__(128) void heads_finish_kernel(
    const float* __restrict__ L, const float* __restrict__ props,
    float* __restrict__ scores, float* __restrict__ boxes,
    int* __restrict__ labels, float* __restrict__ mboxes)
{
    __shared__ float lg[NUM_CLASSES];
    __shared__ float red[2];
    __shared__ int slab;
    int r = blockIdx.x, t = threadIdx.x;
    const float* Lr = L + (size_t)r*512;
    if (t < NUM_CLASSES) lg[t] = Lr[t];
    __syncthreads();
    if (t == 0) {
        float mx = lg[0];
        for (int j = 1; j < NUM_CLASSES; ++j) mx = fmaxf(mx, lg[j]);
        red[0] = mx;
    }
    __syncthreads();
    float mx = red[0];
    if (t < NUM_CLASSES) lg[t] = expf(lg[t] - mx);
    __syncthreads();
    if (t == 0) {
        float s = 0.f;
        int best = 1; float bv = lg[1];
        for (int j = 0; j < NUM_CLASSES; ++j) {
            s += lg[j];
            if (j >= 1 && lg[j] > bv) { bv = lg[j]; best = j; }
        }
        red[1] = 1.f/s;
        slab = best;
    }
    __syncthreads();
    if (t < NUM_CLASSES) scores[(size_t)r*NUM_CLASSES + t] = lg[t]*red[1];

    bool sel = (r < 128) || (r >= 512 && r < 640);
    int mi = (r < 128) ? r : r - 384;
    if (t == 0 && sel) labels[mi] = slab;

    if (t < NUM_CLASSES) {
        float px1 = props[r*4+0], py1 = props[r*4+1];
        float px2 = props[r*4+2], py2 = props[r*4+3];
        float pw = px2 - px1, ph = py2 - py1;
        float cx = px1 + 0.5f*pw, cy = py1 + 0.5f*ph;
        const float* dl = Lr + 81 + t*4;
        float d0 = dl[0] * 0.1f;
        float d1 = dl[1] * 0.1f;
        float d2 = fminf(dl[2] * 0.2f, LOG1000_16);
        float d3 = fminf(dl[3] * 0.2f, LOG1000_16);
        float pcx = d0*pw + cx, pcy = d1*ph + cy;
        float qw = expf(d2)*pw, qh = expf(d3)*ph;
        float b0 = fminf(fmaxf(pcx - 0.5f*qw, 0.f), 800.f);
        float b1 = fminf(fmaxf(pcy - 0.5f*qh, 0.f), 800.f);
        float b2 = fminf(fmaxf(pcx + 0.5f*qw, 0.f), 800.f);
        float b3 = fminf(fmaxf(pcy + 0.5f*qh, 0.f), 800.f);
        size_t ob = ((size_t)r*NUM_CLASSES + t)*4;
        boxes[ob+0] = b0; boxes[ob+1] = b1; boxes[ob+2] = b2; boxes[ob+3] = b3;
        if (sel && t == slab) {
            mboxes[mi*4+0] = b0; mboxes[mi*4+1] = b1;
            mboxes[mi*4+2] = b2; mboxes[mi*4+3] = b3;
        }
    }
}

// ---------------------------------------------------------------------------
// K6: roi_align 14x14 -> transposed fp16 actT[mi][p][c]. Block=(roi,32ch grp).
// ---------------------------------------------------------------------------
__global__ __launch_bounds__(256) void roi_align14_kernel(
    const float* __restrict__ f0, const float* __restrict__ f1,
    const float* __restrict__ f2, const float* __restrict__ f3,
    const float* __restrict__ mboxes, const int* __restrict__ bidx,
    _Float16* __restrict__ outT)
{
    int mi = blockIdx.x;
    int cg = blockIdx.y;          // 8 groups of 32 channels
    int t = threadIdx.x;
    if (t >= 196) return;
    int oy = t / 14, ox = t % 14;

    float x1 = mboxes[mi*4+0], y1 = mboxes[mi*4+1];
    float x2 = mboxes[mi*4+2], y2 = mboxes[mi*4+3];
    float area = fmaxf(x2-x1, 0.f) * fmaxf(y2-y1, 0.f);
    float lf = floorf(4.f + log2f(sqrtf(area)/224.f + 1e-6f));
    lf = fminf(fmaxf(lf, 2.f), 5.f);
    int lvl = (int)lf - 2;

    const float* feat; int H, W; float scale;
    if (lvl == 0)      { feat = f0; H = 200; W = 200; scale = 0.25f; }
    else if (lvl == 1) { feat = f1; H = 100; W = 100; scale = 0.125f; }
    else if (lvl == 2) { feat = f2; H = 50;  W = 50;  scale = 0.0625f; }
    else               { feat = f3; H = 25;  W = 25;  scale = 0.03125f; }
    int ridx = (mi < 128) ? mi : mi + 384;
    int b = bidx[ridx];

    float x1s = x1*scale, y1s = y1*scale;
    float rw = fmaxf(x2*scale - x1s, 1.f);
    float rh = fmaxf(y2*scale - y1s, 1.f);

    int   offs[4];
    float w00[4], w01[4], w10[4], w11[4];
    #pragma unroll
    for (int sy = 0; sy < 2; ++sy) {
        int iy = oy*2 + sy;
        float gy = ((float)iy + 0.5f) / 28.f;
        float yc = y1s + rh*gy;
        bool  yv = (yc > -1.f) && (yc < (float)H);
        float ycl = fminf(fmaxf(yc, 0.f), (float)(H-1));
        int   y0  = (int)fminf(floorf(ycl), (float)(H-2));
        float ly  = ycl - (float)y0;
        #pragma unroll
        for (int sx = 0; sx < 2; ++sx) {
            int ix = ox*2 + sx;
            float gx = ((float)ix + 0.5f) / 28.f;
            float xc = x1s + rw*gx;
            bool  xv = (xc > -1.f) && (xc < (float)W);
            float xcl = fminf(fmaxf(xc, 0.f), (float)(W-1));
            int   x0  = (int)fminf(floorf(xcl), (float)(W-2));
            float lx  = xcl - (float)x0;
            float m = (yv && xv) ? 1.f : 0.f;
            int s = sy*2 + sx;
            offs[s] = y0*W + x0;
            w00[s] = (1.f-ly)*(1.f-lx)*m;
            w01[s] = (1.f-ly)*lx*m;
            w10[s] = ly*(1.f-lx)*m;
            w11[s] = ly*lx*m;
        }
    }

    size_t HW = (size_t)H * W;
    _Float16* orow = outT + ((size_t)mi*196 + t)*CDIM + cg*32;
    const float* fbase = feat + ((size_t)b*CDIM + cg*32) * HW;
    #pragma unroll
    for (int c8 = 0; c8 < 32; c8 += 8) {
        half8v hv;
        #pragma unroll
        for (int cc = 0; cc < 8; ++cc) {
            const float* fb = fbase + (size_t)(c8+cc) * HW;
            float acc = 0.f;
            #pragma unroll
            for (int s = 0; s < 4; ++s) {
                const float* q = fb + offs[s];
                acc += w00[s]*q[0] + w01[s]*q[1] + w10[s]*q[W] + w11[s]*q[W+1];
            }
            hv[cc] = (_Float16)(acc * 0.25f);
        }
        *(half8v*)(orow + c8) = hv;
    }
}

// ---------------------------------------------------------------------------
// Weight repacks (conv / deconv)
// ---------------------------------------------------------------------------
__global__ __launch_bounds__(256) void repack_wts_kernel(
    const float* __restrict__ w, _Float16* __restrict__ Wr)
{
    int i = blockIdx.x*256 + threadIdx.x;   // 4*9*256*256
    int ci = i & 255;
    int rest = i >> 8;
    int co = rest & 255;
    int rest2 = rest >> 8;
    int tap = rest2 % 9;
    int l = rest2 / 9;
    Wr[i] = (_Float16)w[(((size_t)(l*256 + co)*256 + ci)*9) + tap];
}

// deconv_w[c][o][p][q] fp32 -> Wd[n=o*4+p*2+q][c] fp16  (pure transpose)
__global__ __launch_bounds__(256) void repack_dw_kernel(
    const float* __restrict__ dw, _Float16* __restrict__ Wd)
{
    int i = blockIdx.x*256 + threadIdx.x;   // 1024*256
    int n = i >> 8, k = i & 255;
    Wd[i] = (_Float16)dw[(size_t)k*1024 + n];
}

// ---------------------------------------------------------------------------
// K7: conv3x3+bias+relu as fp16 MFMA implicit GEMM.
// ---------------------------------------------------------------------------
#define PSTR 40

__global__ __launch_bounds__(256) void conv3x3_mfma_kernel(
    const _Float16* __restrict__ inT, const _Float16* __restrict__ Wr,
    const float* __restrict__ bias, _Float16* __restrict__ outT, int layer)
{
    __shared__ _Float16 lin[256*PSTR];   // 20 KiB

    int t = threadIdx.x;
    int lane = t & 63;
    int wave = t >> 6;
    int ln = lane & 15;
    int q  = lane >> 4;
    int q8 = q*8;
    int r  = blockIdx.x >> 2;
    int bc = blockIdx.x & 3;
    int co_w = bc*64 + wave*16;

    const _Float16* WrL = Wr + (size_t)layer*9*256*256;
    const _Float16* inR = inT + (size_t)r*196*256;

    for (int i = t; i < 256*PSTR; i += 256) lin[i] = (_Float16)0.f;

    float4v acc[13];
    #pragma unroll
    for (int nt = 0; nt < 13; ++nt) acc[nt] = (float4v){0.f,0.f,0.f,0.f};

    for (int ci0 = 0; ci0 < 256; ci0 += 32) {
        __syncthreads();
        for (int idx = t; idx < 784; idx += 256) {
            int p = idx >> 2, g = idx & 3;
            float4 v = *(const float4*)(inR + (size_t)p*256 + ci0 + g*8);
            int row = (p*37450) >> 19;
            int col = p - row*14;
            *(float4*)&lin[((row+1)*16 + (col+1))*PSTR + g*8] = v;
        }
        __syncthreads();

        half8v aw[9];
        #pragma unroll
        for (int tap = 0; tap < 9; ++tap)
            aw[tap] = *(const half8v*)(WrL + ((size_t)tap*256 + co_w + ln)*256 + ci0 + q8);

        #pragma unroll
        for (int nt = 0; nt < 13; ++nt) {
            int n = nt*16 + ln;
            int row = (n*37450) >> 19;
            int col = n - row*14;
            int pb = (n < 196) ? (row*16 + col) : 0;
            const _Float16* bp = &lin[pb*PSTR + q8];
            #pragma unroll
            for (int ky = 0; ky < 3; ++ky) {
                #pragma unroll
                for (int kx = 0; kx < 3; ++kx) {
                    half8v bv = *(const half8v*)(bp + (ky*16 + kx)*PSTR);
                    acc[nt] = __builtin_amdgcn_mfma_f32_16x16x32_f16(
                        aw[ky*3+kx], bv, acc[nt], 0, 0, 0);
                }
            }
        }
    }

    float4 bi = *(const float4*)&bias[layer*256 + co_w + q*4];
    float bia[4] = {bi.x, bi.y, bi.z, bi.w};
    #pragma unroll
    for (int nt = 0; nt < 13; ++nt) {
        int n = nt*16 + ln;
        if (n < 196) {
            half4v hv;
            #pragma unroll
            for (int i = 0; i < 4; ++i)
                hv[i] = (_Float16)fmaxf(acc[nt][i] + bia[i], 0.f);
            *(half4v*)(outT + ((size_t)r*196 + n)*256 + co_w + q*4) = hv;
        }
    }
}

// ---------------------------------------------------------------------------
// K8: deconv+mask head, fp16 MFMA per-roi GEMM with fused epilogue.
// ---------------------------------------------------------------------------
#define DSTR 264   // LDS act row stride in halves (528 B, 16B-aligned)

template<int NMT>
__device__ __forceinline__ void deconv_pass(
    const _Float16* actL, const _Float16* __restrict__ Wd,
    const float* __restrict__ db, const float* __restrict__ mlw,
    int lab, float (*sred)[4], int wv, int ln, int q, int px0)
{
    float P[NMT][4];
    #pragma unroll
    for (int mt = 0; mt < NMT; ++mt)
        #pragma unroll
        for (int r2 = 0; r2 < 4; ++r2) P[mt][r2] = 0.f;

    for (int c = 0; c < 8; ++c) {
        int n0 = wv*256 + c*32;
        float4v acc[NMT][2];
        #pragma unroll
        for (int mt = 0; mt < NMT; ++mt) {
            acc[mt][0] = (float4v){0.f,0.f,0.f,0.f};
            acc[mt][1] = (float4v){0.f,0.f,0.f,0.f};
        }
        #pragma unroll
        for (int k = 0; k < 8; ++k) {
            const _Float16* wp = Wd + ((size_t)(n0 + ln))*256 + k*32 + q*8;
            half8v b0 = *(const half8v*)wp;
            half8v b1 = *(const half8v*)(wp + 16*256);
            #pragma unroll
            for (int mt = 0; mt < NMT; ++mt) {
                half8v a = *(const half8v*)&actL[(mt*16 + ln)*DSTR + k*32 + q*8];
                acc[mt][0] = __builtin_amdgcn_mfma_f32_16x16x32_f16(
                    a, b0, acc[mt][0], 0, 0, 0);
                acc[mt][1] = __builtin_amdgcn_mfma_f32_16x16x32_f16(
                    a, b1, acc[mt][1], 0, 0, 0);
            }
        }
        #pragma unroll
        for (int j = 0; j < 2; ++j) {
            int n = n0 + j*16 + ln;
            int o = n >> 2;
            float bo = db[o];
            float wl = mlw[lab*256 + o];
            #pragma unroll
            for (int mt = 0; mt < NMT; ++mt)
                #pragma unroll
                for (int r2 = 0; r2 < 4; ++r2)
                    P[mt][r2] += fmaxf(acc[mt][j][r2] + bo, 0.f) * wl;
        }
    }
    #pragma unroll
    for (int mt = 0; mt < NMT; ++mt)
        #pragma unroll
        for (int r2 = 0; r2 < 4; ++r2) {
            float v = P[mt][r2];
            v += __shfl_xor(v, 4);
            v += __shfl_xor(v, 8);
            int px = px0 + mt*16 + q*4 + r2;
            if (ln < 4 && px < 196) atomicAdd(&sred[px][ln], v);
        }
}

__global__ __launch_bounds__(256, 1) void deconv_mask_mfma_kernel(
    const _Float16* __restrict__ mfT, const _Float16* __restrict__ Wd,
    const float* __restrict__ db, const float* __restrict__ mlw,
    const float* __restrict__ mlb, const int* __restrict__ labels,
    float* __restrict__ masks)
{
    __shared__ _Float16 act[112*DSTR];   // 59136 B
    __shared__ float sred[196][4];       //  3136 B
    int t = threadIdx.x;
    int lane = t & 63, wv = t >> 6, ln = lane & 15, q = lane >> 4;
    int mi = blockIdx.x;
    int lab = labels[mi];

    for (int i = t; i < 784; i += 256) ((float*)sred)[i] = 0.f;

    for (int idx = t; idx < 112*32; idx += 256) {
        int px = idx >> 5, g = idx & 31;
        *(float4*)&act[px*DSTR + g*8] =
            *(const float4*)(mfT + ((size_t)mi*196 + px)*256 + g*8);
    }
    __syncthreads();
    deconv_pass<7>(act, Wd, db, mlw, lab, sred, wv, ln, q, 0);
    __syncthreads();

    for (int idx = t; idx < 84*32; idx += 256) {
        int px = idx >> 5, g = idx & 31;
        *(float4*)&act[px*DSTR + g*8] =
            *(const float4*)(mfT + ((size_t)mi*196 + 112 + px)*256 + g*8);
    }
    __syncthreads();
    deconv_pass<6>(act, Wd, db, mlw, lab, sred, wv, ln, q, 112);
    __syncthreads();

    if (t < 196) {
        float bl = mlb[lab];
        int i2 = t / 14, j2 = t % 14;
        #pragma unroll
        for (int pq = 0; pq < 4; ++pq) {
            float s = sred[t][pq] + bl;
            int h = 2*i2 + (pq >> 1), w2 = 2*j2 + (pq & 1);
            masks[(size_t)mi*784 + h*28 + w2] = 1.f/(1.f + expf(-s));
        }
    }
}

// ---------------------------------------------------------------------------
extern "C" void kernel_launch(void* const* d_in, const int* in_sizes, int n_in,
                              void* d_out, int out_size, void* d_ws, size_t ws_size,
                              hipStream_t stream) {
    const float* f0      = (const float*)d_in[0];
    const float* f1      = (const float*)d_in[1];
    const float* f2      = (const float*)d_in[2];
    const float* f3      = (const float*)d_in[3];
    const float* props   = (const float*)d_in[4];
    const float* fc1_w   = (const float*)d_in[5];
    const float* fc1_b   = (const float*)d_in[6];
    const float* fc2_w   = (const float*)d_in[7];
    const float* fc2_b   = (const float*)d_in[8];
    const float* cls_w   = (const float*)d_in[9];
    const float* cls_b   = (const float*)d_in[10];
    const float* bbox_w  = (const float*)d_in[11];
    const float* bbox_b  = (const float*)d_in[12];
    const float* mconv_w = (const float*)d_in[13];
    const float* mconv_b = (const float*)d_in[14];
    const float* dconv_w = (const float*)d_in[15];
    const float* dconv_b = (const float*)d_in[16];
    const float* mlog_w  = (const float*)d_in[17];
    const float* mlog_b  = (const float*)d_in[18];
    const int*   bidx    = (const int*)d_in[19];

    // workspace layout (bytes)
    char* wsb = (char*)d_ws;
    float*    bf   = (float*)wsb;                    // [0, 51.38MB)
    _Float16* bufA = (_Float16*)wsb;                 // alias: conv ping
    _Float16* bufB = (_Float16*)(wsb + 25690112);    // conv pong
    float*    x1   = (float*)(wsb + 51380224);       // 4MB
    float*    x2   = (float*)(wsb + 55574528);       // 4MB
    int*      labels = (int*)(wsb + 59768832);       // 4KB pad
    float*    mboxes = (float*)(wsb + 59772928);     // 8KB pad
    float*    Cp     = (float*)(wsb + 59781120);     // 16MB partials
    _Float16* Wr     = (_Float16*)(wsb + 59781120);  // alias Cp (after heads)
    _Float16* Wd     = (_Float16*)(wsb + 64499712);  // alias Cp (after heads)
    float*    Wcat   = (float*)(wsb + 76558336);     // 2MB
    float*    bcat   = (float*)(wsb + 78655488);     // 2KB (pad to 4KB)
    float*    Lh     = (float*)(wsb + 78659584);     // 2MB logits+deltas

    float* scores = (float*)d_out;
    float* boxes  = scores + RTOT*NUM_CLASSES;
    float* masks  = boxes + RTOT*NUM_CLASSES*4;

    // K1: roi_align 7x7 -> bf  (channel-split: 4 groups)
    roi_align7_kernel<<<dim3(RTOT, 4), 256, 0, stream>>>(
        f0, f1, f2, f3, props, bidx, bf);

    // head weight concat (independent of fc phase)
    repack_head_kernel<<<2048, 256, 0, stream>>>(cls_w, cls_b, bbox_w, bbox_b,
                                                 Wcat, bcat);

    // K2: fc1 (split-fp16 MFMA, block 64x128, split-K=4 -> 512 blocks)
    gemm_splitk_f16x3<<<dim3(8, 16, 4), 256, 0, stream>>>(
        bf, fc1_w, Cp, 12544, 3136, 1024);
    fc_reduce_kernel<<<1024, 256, 0, stream>>>(Cp, fc1_b, x1, 4, 256, 1);

    // K3: fc2 (split-K=4, KS=256)
    gemm_splitk_f16x3<<<dim3(8, 16, 4), 256, 0, stream>>>(
        x1, fc2_w, Cp, 1024, 256, 1024);
    fc_reduce_kernel<<<1024, 256, 0, stream>>>(Cp, fc2_b, x2, 4, 256, 1);

    // K4: head GEMM: L = x2 @ Wcat^T + bcat  (M=1024, N=512, K=1024)
    gemm_splitk_f16x3<<<dim3(4, 16, 4), 256, 0, stream>>>(
        x2, Wcat, Cp, 1024, 256, 512);
    fc_reduce_kernel<<<512, 256, 0, stream>>>(Cp, bcat, Lh, 4, 128, 0);

    // K5: softmax/argmax/decode from precomputed L
    heads_finish_kernel<<<RTOT, 128, 0, stream>>>(Lh, props, scores, boxes,
                                                  labels, mboxes);

    // W0: conv/deconv weight repacks (Cp now dead -> Wr/Wd alias it)
    repack_wts_kernel<<<4*9*256, 256, 0, stream>>>(mconv_w, Wr);
    repack_dw_kernel<<<1024, 256, 0, stream>>>(dconv_w, Wd);

    // K6: roi_align 14x14 -> bufA (channel-split: 8 groups)
    roi_align14_kernel<<<dim3(RMASK, 8), 256, 0, stream>>>(
        f0, f1, f2, f3, mboxes, bidx, bufA);

    // K7: 4x conv3x3 MFMA, ping-pong A->B->A->B->A
    conv3x3_mfma_kernel<<<RMASK*4, 256, 0, stream>>>(bufA, Wr, mconv_b, bufB, 0);
    conv3x3_mfma_kernel<<<RMASK*4, 256, 0, stream>>>(bufB, Wr, mconv_b, bufA, 1);
    conv3x3_mfma_kernel<<<RMASK*4, 256, 0, stream>>>(bufA, Wr, mconv_b, bufB, 2);
    conv3x3_mfma_kernel<<<RMASK*4, 256, 0, stream>>>(bufB, Wr, mconv_b, bufA, 3);

    // K8: fused deconv + mask head (MFMA)
    deconv_mask_mfma_kernel<<<RMASK, 256, 0, stream>>>(bufA, Wd, dconv_b, mlog_w,
                                                       mlog_b, labels, masks);
}